// Round 9
// baseline (1444.480 us; speedup 1.0000x reference)
//
#include <hip/hip_runtime.h>
#include <stdint.h>

// Problem constants
constexpr int Nn     = 20000;    // nodes
constexpr int Ee     = 640000;   // edges
constexpr int NPERMc = 20000;    // permutations (R = NPERM*16)

using bf16x8 = __attribute__((ext_vector_type(8))) short;
using f32x4  = __attribute__((ext_vector_type(4))) float;
using s16x4  = __attribute__((ext_vector_type(4))) short;
using u16x8  = __attribute__((ext_vector_type(8))) unsigned short;
using u16x4  = __attribute__((ext_vector_type(4))) unsigned short;

__device__ __forceinline__ short f2bf(float f) {
  union { float f; unsigned u; } v; v.f = f;
  unsigned r = v.u + 0x7FFFu + ((v.u >> 16) & 1u);   // RNE
  return (short)(r >> 16);
}
__device__ __forceinline__ float bf2f(unsigned short s) {
  union { unsigned u; float f; } v; v.u = ((unsigned)s) << 16;
  return v.f;
}
__device__ __forceinline__ f32x4 MFMA(bf16x8 a, bf16x8 b, f32x4 c) {
  return __builtin_amdgcn_mfma_f32_16x16x32_bf16(a, b, c, 0, 0, 0);
}

// LDS A-frag swizzle: XOR bits 7-9 of the short-index into bits 3-5.
// Self-consistent (write and read both apply it); preserves 16B alignment
// of b128 reads. Kills the 8-way bank conflict of stage16x128's ds_writes.
__device__ __forceinline__ int swz(int s) { return s ^ (((s >> 7) & 7) << 3); }

// frag-linear layout for B operand (B[k][n]) of 16x16x32:
// lane l holds B[kk*32 + 8*(l/16)+j][t*16 + l%16], stored as
// shorts at ((t*4+kk)*64 + lane)*8 + j  -> conflict-free ds_read_b128
__device__ __forceinline__ int fragIdx(int k, int n) {
  int t = n >> 4, kk = k >> 5;
  int l = ((k & 31) >> 3) * 16 + (n & 15);
  int j = k & 7;
  return ((t * 4 + kk) * 64 + l) * 8 + j;
}

// Stage 16 rows x 128 cols of fp32 into wave-private LDS in A-frag order (bf16).
__device__ __forceinline__ void stage16x128(const float* __restrict__ src, int row0, int M,
                                            int lane, short* lds) {
  #pragma unroll
  for (int it = 0; it < 8; ++it) {
    int u = it * 64 + lane;
    int r = u >> 5;          // row within tile 0..15
    int q = u & 31;          // float4 index within row
    int row = row0 + r;
    float4 v = make_float4(0.f, 0.f, 0.f, 0.f);
    if (row < M) v = ((const float4*)(src + (size_t)row * 128))[q];
    int k  = q * 4;
    int kk = k >> 5;
    int l2 = ((k & 31) >> 3) * 16 + r;
    int j  = k & 7;
    s16x4 s4 = { f2bf(v.x), f2bf(v.y), f2bf(v.z), f2bf(v.w) };
    *(s16x4*)(lds + swz((kk * 64 + l2) * 8 + j)) = s4;
  }
}

// ---------------------------------------------------------------------------
// kPrep: fold all small weight products on-device, emit bf16 frag-order weights
// ---------------------------------------------------------------------------
__global__ __launch_bounds__(256) void kPrep(
    const float* __restrict__ in_w,  const float* __restrict__ out_w,
    const float* __restrict__ src_w, const float* __restrict__ dst_w,
    const float* __restrict__ nloop_w, const float* __restrict__ eloop_w,
    const float* __restrict__ lrp_w,
    const float* __restrict__ nbias, const float* __restrict__ ebias,
    const float* __restrict__ w1e, const float* __restrict__ b1e,
    const float* __restrict__ w1n, const float* __restrict__ b1n,
    const float* __restrict__ w2e, const float* __restrict__ w2n,
    short* __restrict__ WA, short* __restrict__ BQ, short* __restrict__ WN,
    short* __restrict__ W2E, short* __restrict__ W2N, short* __restrict__ WL,
    float* __restrict__ c0e, float* __restrict__ c0n) {
  __shared__ float Rl[16384];          // 64KB: right matrix cached
  int tid = threadIdx.x;
  int blk = blockIdx.x;
  if (blk < 448) {                     // 7 products x 64 blocks
    int p = blk >> 6, sub = blk & 63;
    const float* La; const float* Lb = nullptr; const float* R; short* outp;
    float sOut = 1.f;
    switch (p) {
      case 0: La = eloop_w;             R = w1e; outp = WA;          break;
      case 1: La = src_w; Lb = dst_w;   R = w1e; outp = WA + 16384;  break;
      case 2: La = dst_w;               R = w1e; outp = BQ;          break;
      case 3: La = src_w;               R = w1e; outp = BQ + 16384;  break;
      case 4: La = nloop_w;             R = w1n; outp = WN;          break;
      case 5: La = out_w;               R = w1n; outp = WN + 16384;  break;
      default: La = in_w;               R = w1n; outp = WN + 32768; sOut = -1.f; break;
    }
    for (int i = tid; i < 16384; i += 256) Rl[i] = R[i];
    __syncthreads();
    int e = sub * 256 + tid;
    int k = e >> 7, n = e & 127;
    float acc = 0.f;
    bool hasLb = (Lb != nullptr);
    for (int j = 0; j < 128; ++j) {
      float l = La[k * 128 + j];
      if (hasLb) l -= Lb[k * 128 + j];
      acc += l * Rl[j * 128 + n];
    }
    outp[fragIdx(k, n)] = f2bf(acc * sOut);
  } else if (blk < 512) {              // w2e conversion
    int e = (blk - 448) * 256 + tid; int k = e >> 7, n = e & 127;
    W2E[fragIdx(k, n)] = f2bf(w2e[k * 128 + n]);
  } else if (blk < 576) {              // w2n conversion
    int e = (blk - 512) * 256 + tid; int k = e >> 7, n = e & 127;
    W2N[fragIdx(k, n)] = f2bf(w2n[k * 128 + n]);
  } else if (blk < 1600) {             // lrp_w: 16 a-matrices, B[k=b][n=c] = lrp_w[b][c][a]
    int q = blk - 576; int a = q >> 6;
    int e = (q & 63) * 256 + tid; int k = e >> 7, n = e & 127;
    WL[a * 16384 + fragIdx(k, n)] = f2bf(lrp_w[(k * 128 + n) * 16 + a]);
  } else {                             // c0e = ebias@w1e + b1e ; c0n = nbias@w1n + b1n
    if (tid < 128) {
      float acc = 0.f;
      for (int k2 = 0; k2 < 128; ++k2) acc += ebias[k2] * w1e[k2 * 128 + tid];
      c0e[tid] = acc + b1e[tid];
    } else {
      int n = tid - 128; float acc = 0.f;
      for (int k2 = 0; k2 < 128; ++k2) acc += nbias[k2] * w1n[k2 * 128 + n];
      c0n[n] = acc + b1n[n];
    }
  }
}

// ---------------------------------------------------------------------------
// Aggregation: counting sort by dst, then gather-reduce (no fp32 atomics).
// ---------------------------------------------------------------------------

// kHist: per-dst edge counts (int) + out-degree by src (float, used by kD)
__global__ __launch_bounds__(256) void kHist(
    const int* __restrict__ srcI, const int* __restrict__ dstI,
    int* __restrict__ cnt, float* __restrict__ deg) {
  int e = blockIdx.x * 256 + threadIdx.x;
  atomicAdd(&cnt[dstI[e]], 1);
  atomicAdd(&deg[srcI[e]], 1.0f);
}

// kScan: exclusive prefix sum over Nn bins -> off[] (CSR starts) and cur[] (cursors)
__global__ __launch_bounds__(256) void kScan(const int* __restrict__ cnt,
                                             int* __restrict__ off,
                                             int* __restrict__ cur) {
  __shared__ int lc[Nn];               // 80 KB
  __shared__ int ps[256];
  int tid = threadIdx.x;
  for (int i = tid; i < Nn; i += 256) lc[i] = cnt[i];
  __syncthreads();
  constexpr int CH = (Nn + 255) / 256; // 79 bins per thread
  int base = tid * CH;
  int local = 0;
  for (int i = 0; i < CH; ++i) {
    int idx = base + i;
    if (idx < Nn) local += lc[idx];
  }
  ps[tid] = local;
  __syncthreads();
  for (int d = 1; d < 256; d <<= 1) {  // Hillis-Steele inclusive scan
    int t = (tid >= d) ? ps[tid - d] : 0;
    __syncthreads();
    if (tid >= d) ps[tid] += t;
    __syncthreads();
  }
  int run = ps[tid] - local;           // exclusive prefix at chunk start
  for (int i = 0; i < CH; ++i) {
    int idx = base + i;
    if (idx < Nn) { off[idx] = run; cur[idx] = run; run += lc[idx]; }
  }
}

// kScatter: place edge ids into dst-sorted order; rev flag packed in sign bit.
// Also precompute per-edge degree scale (deg is L2-hot here) so kD reads it
// coalesced instead of doing a random 4B gather in the hot kernel.
__global__ __launch_bounds__(256) void kScatter(
    const int* __restrict__ dstI, const int* __restrict__ revI,
    int* __restrict__ cur, int* __restrict__ order,
    const float* __restrict__ deg, float* __restrict__ sclE) {
  int e = blockIdx.x * 256 + threadIdx.x;
  int d = dstI[e];
  int pos = atomicAdd(&cur[d], 1);
  order[pos] = revI[e] ? (e | (int)0x80000000) : e;
  sclE[e] = 2.0f * (1.0f + log2f(1.0f + deg[d]));
}

// kAgg2: one wave per node; gather 512B edge rows, accumulate in registers.
// (R5-proven unroll-4 float2 form)
__global__ __launch_bounds__(256) void kAgg2(
    const float* __restrict__ ef, const int* __restrict__ off,
    const int* __restrict__ cnt, const int* __restrict__ order,
    float* __restrict__ aggR, float* __restrict__ aggN) {
  int w = threadIdx.x >> 6, lane = threadIdx.x & 63;
  int n = blockIdx.x * 4 + w;
  if (n >= Nn) return;
  int s0 = off[n], c = cnt[n];
  float2 aR = make_float2(0.f, 0.f), aN = make_float2(0.f, 0.f);
  int i = 0;
  for (; i + 3 < c; i += 4) {          // unroll 4: more loads in flight
    int oe0 = order[s0 + i];
    int oe1 = order[s0 + i + 1];
    int oe2 = order[s0 + i + 2];
    int oe3 = order[s0 + i + 3];
    float2 v0 = ((const float2*)(ef + (size_t)(oe0 & 0x7fffffff) * 128))[lane];
    float2 v1 = ((const float2*)(ef + (size_t)(oe1 & 0x7fffffff) * 128))[lane];
    float2 v2 = ((const float2*)(ef + (size_t)(oe2 & 0x7fffffff) * 128))[lane];
    float2 v3 = ((const float2*)(ef + (size_t)(oe3 & 0x7fffffff) * 128))[lane];
    if (oe0 < 0) { aR.x += v0.x; aR.y += v0.y; } else { aN.x += v0.x; aN.y += v0.y; }
    if (oe1 < 0) { aR.x += v1.x; aR.y += v1.y; } else { aN.x += v1.x; aN.y += v1.y; }
    if (oe2 < 0) { aR.x += v2.x; aR.y += v2.y; } else { aN.x += v2.x; aN.y += v2.y; }
    if (oe3 < 0) { aR.x += v3.x; aR.y += v3.y; } else { aN.x += v3.x; aN.y += v3.y; }
  }
  for (; i < c; ++i) {
    int oe = order[s0 + i];
    int e = oe & 0x7fffffff;
    float2 v = ((const float2*)(ef + (size_t)e * 128))[lane];
    if (oe < 0) { aR.x += v.x; aR.y += v.y; } else { aN.x += v.x; aN.y += v.y; }
  }
  ((float2*)(aggR + (size_t)n * 128))[lane] = aR;
  ((float2*)(aggN + (size_t)n * 128))[lane] = aN;
}

// ---------------------------------------------------------------------------
// kQ: Q[n] = nf@(dst_w@w1e) | nf@(src_w@w1e), stored HALF-PERMUTED in BF16:
// Qb[n][h*128 + m*8 + tt] = bf16(Qlogical[n][h*128 + tt*16 + m])
// ---------------------------------------------------------------------------
__global__ __launch_bounds__(256, 2) void kQ(const float* __restrict__ nf,
                                             const short* __restrict__ BQ,
                                             short* __restrict__ Qb, int M) {
  __shared__ __align__(16) short alds[4][2048];
  __shared__ __align__(16) short wbuf[8192];     // 16 tiles x 64 x 8 for current kk
  int tid = threadIdx.x, w = tid >> 6, lane = tid & 63;
  int row0 = blockIdx.x * 64 + w * 16;
  stage16x128(nf, row0, M, lane, alds[w]);
  f32x4 acc[16];
  #pragma unroll
  for (int t = 0; t < 16; ++t) acc[t] = (f32x4){0.f, 0.f, 0.f, 0.f};
  const int4* g4 = (const int4*)BQ;
  for (int kk = 0; kk < 4; ++kk) {
    __syncthreads();
    for (int c = tid; c < 1024; c += 256) {
      int t = c >> 6, l = c & 63;
      ((int4*)wbuf)[c] = g4[(t * 4 + kk) * 64 + l];
    }
    __syncthreads();
    bf16x8 a = *(const bf16x8*)(alds[w] + swz((kk * 64 + lane) * 8));
    #pragma unroll
    for (int t = 0; t < 16; ++t) {
      bf16x8 b = *(const bf16x8*)(wbuf + (t * 64 + lane) * 8);
      acc[t] = MFMA(a, b, acc[t]);
    }
  }
  int sub = lane >> 4, m = lane & 15;
  #pragma unroll
  for (int i = 0; i < 4; ++i) {
    int row = row0 + sub * 4 + i;
    if (row < M) {
      #pragma unroll
      for (int h = 0; h < 2; ++h) {
        bf16x8 pk;
        #pragma unroll
        for (int tt = 0; tt < 8; ++tt) pk[tt] = f2bf(acc[h * 8 + tt][i]);
        *(bf16x8*)(Qb + (size_t)row * 256 + h * 128 + m * 8) = pk;
      }
    }
  }
}

// ---------------------------------------------------------------------------
// kN1: h_n = nf@G1 + aggR@G2 + aggN@G3n + c0n  (K=384), bf16 out (PERMUTED
// layout: hN[row][m*8+t] = h[row][t*16+m]) + BN partials (dense per-block)
// ---------------------------------------------------------------------------
__global__ __launch_bounds__(256, 2) void kN1(
    const float* __restrict__ nf, const float* __restrict__ aggR,
    const float* __restrict__ aggN, const short* __restrict__ WN,
    const float* __restrict__ c0n, short* __restrict__ hN,
    float* __restrict__ scratchN, int M) {
  __shared__ __align__(16) short alds[4][2048];
  __shared__ __align__(16) short wlds[16384];
  __shared__ float statsLDS[256];
  int tid = threadIdx.x, w = tid >> 6, lane = tid & 63;
  int m = lane & 15, sub = lane >> 4;
  statsLDS[tid] = 0.f;
  int row0 = blockIdx.x * 64 + w * 16;
  f32x4 acc[8];
  #pragma unroll
  for (int t = 0; t < 8; ++t) acc[t] = (f32x4){0.f, 0.f, 0.f, 0.f};
  for (int s = 0; s < 3; ++s) {
    const float* src = (s == 0) ? nf : ((s == 1) ? aggR : aggN);
    __syncthreads();
    const int4* g4 = (const int4*)(WN + s * 16384);
    for (int c = tid; c < 2048; c += 256) ((int4*)wlds)[c] = g4[c];
    __syncthreads();
    stage16x128(src, row0, M, lane, alds[w]);
    for (int kk = 0; kk < 4; ++kk) {
      bf16x8 a = *(const bf16x8*)(alds[w] + swz((kk * 64 + lane) * 8));
      #pragma unroll
      for (int t = 0; t < 8; ++t) {
        bf16x8 b = *(const bf16x8*)(wlds + ((t * 4 + kk) * 64 + lane) * 8);
        acc[t] = MFMA(a, b, acc[t]);
      }
    }
  }
  float c0v[8];
  #pragma unroll
  for (int t = 0; t < 8; ++t) c0v[t] = c0n[t * 16 + m];
  float ss[8], sq[8];
  #pragma unroll
  for (int t = 0; t < 8; ++t) { ss[t] = 0.f; sq[t] = 0.f; }
  #pragma unroll
  for (int i = 0; i < 4; ++i) {
    int row = row0 + sub * 4 + i;
    if (row < M) {
      bf16x8 pk;
      #pragma unroll
      for (int t = 0; t < 8; ++t) {
        float h = acc[t][i] + c0v[t];
        pk[t] = f2bf(h); ss[t] += h; sq[t] += h * h;
      }
      *(bf16x8*)(hN + (size_t)row * 128 + m * 8) = pk;
    }
  }
  #pragma unroll
  for (int t = 0; t < 8; ++t) {
    float a = ss[t], b = sq[t];
    a += __shfl_xor(a, 16, 64); b += __shfl_xor(b, 16, 64);
    a += __shfl_xor(a, 32, 64); b += __shfl_xor(b, 32, 64);
    if (lane < 16) {
      atomicAdd(&statsLDS[t * 16 + lane], a);
      atomicAdd(&statsLDS[128 + t * 16 + lane], b);
    }
  }
  __syncthreads();
  scratchN[(size_t)blockIdx.x * 256 + tid] = statsLDS[tid];   // dense 1KB/block
}

// ---------------------------------------------------------------------------
// kD: h_e = ef@A1 + scl*(ef@A2) + edge_msg-gather(Qb bf16) + c0e ; BN stats
// R9: split-wave 2x2 grid per block (32 rows/block, each wave 16 rows x 64
// cols). Accumulator halves to 32 AGPR -> ~85 total regs -> 5 waves/SIMD
// (launch_bounds(256,5)). R7 math restored: scl in epilogue, Q gathered in
// epilogue where TLP (now 20 waves/CU) hides the random-load latency.
// ---------------------------------------------------------------------------
__global__ __launch_bounds__(256, 5) void kD(
    const float* __restrict__ ef, const short* __restrict__ WA,
    const short* __restrict__ Qb, const float* __restrict__ c0e,
    const int* __restrict__ srcI, const int* __restrict__ dstI,
    const int* __restrict__ revI, const float* __restrict__ sclE,
    short* __restrict__ hE, float* __restrict__ scratchE) {
  __shared__ __align__(16) short alds[2][2048];   // two 16-row tiles, shared by col-pair waves
  __shared__ __align__(16) short wbuf[8192];      // both matrices, one kk slice
  __shared__ float statsLDS[256];
  int tid = threadIdx.x, w = tid >> 6, lane = tid & 63;
  int rg = w >> 1, cg = w & 1;          // row-group, col-group
  int m = lane & 15, sub = lane >> 4;
  statsLDS[tid] = 0.f;
  int row0 = blockIdx.x * 32 + rg * 16;
  // prefetch per-edge index data; Q gathered in epilogue (TLP-hidden)
  float scl[4]; int qa[4], qb[4];
  #pragma unroll
  for (int i = 0; i < 4; ++i) {
    int e = row0 + sub * 4 + i;
    int s_ = srcI[e], d_ = dstI[e], r_ = revI[e];
    scl[i] = sclE[e];
    int na = r_ ? s_ : d_;
    int nb = r_ ? d_ : s_;
    qa[i] = na * 256 + m * 8 + cg * 4;          // first half, this wave's 4 cols
    qb[i] = nb * 256 + 128 + m * 8 + cg * 4;    // second half
  }
  if (cg == 0) stage16x128(ef, row0, Ee, lane, alds[rg]);   // covered by first barrier
  f32x4 acc1[4], acc2[4];
  #pragma unroll
  for (int t = 0; t < 4; ++t) { acc1[t] = (f32x4){0,0,0,0}; acc2[t] = (f32x4){0,0,0,0}; }
  const int4* g4 = (const int4*)WA;
  for (int kk = 0; kk < 4; ++kk) {
    __syncthreads();
    for (int c = tid; c < 1024; c += 256) {
      int mm = c >> 9, t = (c >> 6) & 7, l = c & 63;
      ((int4*)wbuf)[c] = g4[mm * 2048 + (t * 4 + kk) * 64 + l];
    }
    __syncthreads();
    bf16x8 a = *(const bf16x8*)(alds[rg] + swz((kk * 64 + lane) * 8));
    #pragma unroll
    for (int t = 0; t < 4; ++t) {
      int T = cg * 4 + t;
      bf16x8 b1 = *(const bf16x8*)(wbuf + (T * 64 + lane) * 8);
      bf16x8 b2 = *(const bf16x8*)(wbuf + 4096 + (T * 64 + lane) * 8);
      acc1[t] = MFMA(a, b1, acc1[t]);
      acc2[t] = MFMA(a, b2, acc2[t]);
    }
  }
  float c0v[4];
  #pragma unroll
  for (int t = 0; t < 4; ++t) c0v[t] = c0e[(cg * 4 + t) * 16 + m];
  float ss[4], sq[4];
  #pragma unroll
  for (int t = 0; t < 4; ++t) { ss[t] = 0.f; sq[t] = 0.f; }
  #pragma unroll
  for (int i = 0; i < 4; ++i) {
    int e = row0 + sub * 4 + i;
    u16x4 A = *(const u16x4*)(Qb + qa[i]);
    u16x4 B = *(const u16x4*)(Qb + qb[i]);
    s16x4 pk;
    #pragma unroll
    for (int t = 0; t < 4; ++t) {
      float qv = bf2f(A[t]) - bf2f(B[t]);
      float h = acc1[t][i] + scl[i] * acc2[t][i] + qv + c0v[t];
      pk[t] = f2bf(h);
      ss[t] += h; sq[t] += h * h;
    }
    *(s16x4*)(hE + (size_t)e * 128 + m * 8 + cg * 4) = pk;   // permuted: [m*8+T]
  }
  #pragma unroll
  for (int t = 0; t < 4; ++t) {
    float a = ss[t], b = sq[t];
    a += __shfl_xor(a, 16, 64); b += __shfl_xor(b, 16, 64);
    a += __shfl_xor(a, 32, 64); b += __shfl_xor(b, 32, 64);
    if (lane < 16) {
      atomicAdd(&statsLDS[(cg * 4 + t) * 16 + lane], a);
      atomicAdd(&statsLDS[128 + (cg * 4 + t) * 16 + lane], b);
    }
  }
  __syncthreads();
  scratchE[(size_t)blockIdx.x * 256 + tid] = statsLDS[tid];   // dense 1KB/block
}

// ---------------------------------------------------------------------------
// kRed: stage-1 reduce of dense per-block stats [NB][256] -> part [64][256]
// ---------------------------------------------------------------------------
__global__ __launch_bounds__(256) void kRed(const float* __restrict__ scr, int NB,
                                            float* __restrict__ part) {
  int tid = threadIdx.x, b = blockIdx.x;
  float acc = 0.f;
  for (int r = b; r < NB; r += 64)
    acc += scr[(size_t)r * 256 + tid];
  part[b * 256 + tid] = acc;
}

// ---------------------------------------------------------------------------
// kFin: reduce part[64][256] -> s = g*rsqrt(var+eps), t = beta - mu*s
// ---------------------------------------------------------------------------
__global__ __launch_bounds__(256) void kFin(const float* __restrict__ part,
                                            float M, const float* __restrict__ g,
                                            const float* __restrict__ beta,
                                            float* __restrict__ st) {
  __shared__ float red[256];
  __shared__ float red2[256];
  int c = blockIdx.x;     // 0..127
  int tid = threadIdx.x;
  float s = 0.f, q = 0.f;
  if (tid < 64) {
    s = part[tid * 256 + c];
    q = part[tid * 256 + 128 + c];
  }
  red[tid] = s; red2[tid] = q;
  __syncthreads();
  for (int off = 32; off > 0; off >>= 1) {
    if (tid < off) { red[tid] += red[tid + off]; red2[tid] += red2[tid + off]; }
    __syncthreads();
  }
  if (tid == 0) {
    float mu  = red[0] / M;
    float var = red2[0] / M - mu * mu;
    float inv = rsqrtf(var + 1e-5f);
    float sc  = g[c] * inv;
    st[c] = sc;
    st[128 + c] = beta[c] - mu * sc;
  }
}

// ---------------------------------------------------------------------------
// kF: out = relu(h*s + t) @ w2 + b2     (h is in PERMUTED layout [m*8+t])
// w2 staged in 8KB per-kk slices -> LDS 24KB -> 6 blocks/CU.
// ---------------------------------------------------------------------------
__global__ __launch_bounds__(256, 6) void kF(const short* __restrict__ h,
                                             const float* __restrict__ st,
                                             const short* __restrict__ w2f,
                                             const float* __restrict__ b2,
                                             float* __restrict__ outp, int M) {
  __shared__ __align__(16) short alds[4][2048];
  __shared__ __align__(16) short wbuf[4096];    // one kk slice: 8 tiles
  int tid = threadIdx.x, w = tid >> 6, lane = tid & 63;
  int m2 = lane & 15;
  int row0 = blockIdx.x * 64 + w * 16;
  float sc8[8], tb8[8];
  #pragma unroll
  for (int q = 0; q < 8; ++q) {
    int col = q * 16 + m2;
    sc8[q] = st[col]; tb8[q] = st[128 + col];
  }
  #pragma unroll
  for (int it = 0; it < 4; ++it) {
    int r = it * 4 + (lane >> 4);
    int row = row0 + r;
    u16x8 hv = {0, 0, 0, 0, 0, 0, 0, 0};
    if (row < M) hv = *(const u16x8*)(h + (size_t)row * 128 + m2 * 8);
    #pragma unroll
    for (int q = 0; q < 8; ++q) {
      float f = bf2f(hv[q]);
      float v = fmaxf(f * sc8[q] + tb8[q], 0.f);
      int k = q * 16 + m2;
      int kk = k >> 5, l2 = ((k & 31) >> 3) * 16 + r, j = k & 7;
      alds[w][swz((kk * 64 + l2) * 8 + j)] = f2bf(v);
    }
  }
  f32x4 acc[8];
  #pragma unroll
  for (int t = 0; t < 8; ++t) acc[t] = (f32x4){0.f, 0.f, 0.f, 0.f};
  const int4* g4w = (const int4*)w2f;
  for (int kk = 0; kk < 4; ++kk) {
    __syncthreads();
    for (int c = tid; c < 512; c += 256) {
      int t = c >> 6, l = c & 63;
      ((int4*)wbuf)[c] = g4w[(t * 4 + kk) * 64 + l];
    }
    __syncthreads();
    bf16x8 a = *(const bf16x8*)(alds[w] + swz((kk * 64 + lane) * 8));
    #pragma unroll
    for (int t = 0; t < 8; ++t) {
      bf16x8 b = *(const bf16x8*)(wbuf + (t * 64 + lane) * 8);
      acc[t] = MFMA(a, b, acc[t]);
    }
  }
  int sub = lane >> 4;
  #pragma unroll
  for (int t = 0; t < 8; ++t) {
    int col = t * 16 + (lane & 15);
    float bb = b2[col];
    #pragma unroll
    for (int i = 0; i < 4; ++i) {
      int row = row0 + sub * 4 + i;
      if (row < M) outp[(size_t)row * 128 + col] = acc[t][i] + bb;
    }
  }
}

// ---------------------------------------------------------------------------
// kLRP: perm gather -> K=2048 GEMM over 4 of 16 a-matrices per block
// (a-split x4, grid 313*4, R5-proven form: 16KB monolithic wlds per a)
// ---------------------------------------------------------------------------
__global__ __launch_bounds__(256, 2) void kLRP(
    const float* __restrict__ nout, const float* __restrict__ eoutp,
    const int* __restrict__ n2pc, const float* __restrict__ n2pv,
    const int* __restrict__ e2pc, const float* __restrict__ e2pv,
    const int* __restrict__ poolr, const float* __restrict__ poolv,
    const short* __restrict__ WL, const float* __restrict__ lrp_bias,
    float* __restrict__ pooled) {
  __shared__ __align__(16) short alds[4][2048];
  __shared__ __align__(16) short wlds[16384];
  int tid = threadIdx.x, w = tid >> 6, lane = tid & 63;
  int blk = blockIdx.x % 313, g = blockIdx.x / 313;  // g in 0..3
  int row0 = blk * 64 + w * 16;
  int a0 = g * 4;
  f32x4 acc[8];
  #pragma unroll
  for (int t = 0; t < 8; ++t) acc[t] = (f32x4){0.f, 0.f, 0.f, 0.f};
  for (int a = a0; a < a0 + 4; ++a) {
    __syncthreads();
    const int4* g4 = (const int4*)(WL + a * 16384);
    for (int c = tid; c < 2048; c += 256) ((int4*)wlds)[c] = g4[c];
    __syncthreads();
    #pragma unroll
    for (int it = 0; it < 8; ++it) {
      int u = it * 64 + lane;
      int r = u >> 5;
      int q = u & 31;
      int d = row0 + r;
      float4 v = make_float4(0.f, 0.f, 0.f, 0.f);
      if (d < NPERMc) {
        int i = d * 16 + a;
        int nc = n2pc[i]; float nv = n2pv[i];
        int ec = e2pc[i]; float ev = e2pv[i];
        float4 nr = ((const float4*)(nout  + (size_t)nc * 128))[q];
        float4 er = ((const float4*)(eoutp + (size_t)ec * 128))[q];
        v.x = nv * nr.x + ev * er.x;
        v.y = nv * nr.y + ev * er.y;
        v.z = nv * nr.z + ev * er.z;
        v.w = nv * nr.w + ev * er.w;
      }
      int k  = q * 4;
      int kk = k >> 5;
      int l2 = ((k & 31) >> 3) * 16 + r;
      int j  = k & 7;
      s16x4 s4 = { f2bf(v.x), f2bf(v.y), f2bf(v.z), f2bf(v.w) };
      *(s16x4*)(alds[w] + swz((kk * 64 + l2) * 8 + j)) = s4;
    }
    for (int kk = 0; kk < 4; ++kk) {
      bf16x8 aa = *(const bf16x8*)(alds[w] + swz((kk * 64 + lane) * 8));
      #pragma unroll
      for (int t = 0; t < 8; ++t) {
        bf16x8 b = *(const bf16x8*)(wlds + ((t * 4 + kk) * 64 + lane) * 8);
        acc[t] = MFMA(aa, b, acc[t]);
      }
    }
  }
  int sub = lane >> 4;
  #pragma unroll
  for (int t = 0; t < 8; ++t) {
    int col = t * 16 + (lane & 15);
    float lb = (g == 0) ? lrp_bias[col] : 0.f;
    #pragma unroll
    for (int i = 0; i < 4; ++i) {
      int d = row0 + sub * 4 + i;
      if (d < NPERMc) {
        float val = acc[t][i] + lb;
        atomicAdd(&pooled[poolr[d] * 128 + col], poolv[d] * val);
      }
    }
  }
}

// ---------------------------------------------------------------------------
extern "C" void kernel_launch(void* const* d_in, const int* in_sizes, int n_in,
                              void* d_out, int out_size, void* d_ws, size_t ws_size,
                              hipStream_t stream) {
  (void)in_sizes; (void)n_in; (void)out_size; (void)ws_size;
  const float* node_feat = (const float*)d_in[0];
  const float* edge_feat = (const float*)d_in[1];
  const int*   srcI      = (const int*)d_in[2];
  const int*   dstI      = (const int*)d_in[3];
  const int*   revI      = (const int*)d_in[4];
  const int*   n2pc      = (const int*)d_in[5];
  const float* n2pv      = (const float*)d_in[6];
  const int*   e2pc      = (const int*)d_in[7];
  const float* e2pv      = (const float*)d_in[8];
  const int*   poolr     = (const int*)d_in[9];
  const float* poolv     = (const float*)d_in[10];
  const float* in_w      = (const float*)d_in[11];
  const float* out_w     = (const float*)d_in[12];
  const float* src_w     = (const float*)d_in[13];
  const float* dst_w     = (const float*)d_in[14];
  const float* nloop_w   = (const float*)d_in[15];
  const float* eloop_w   = (const float*)d_in[16];
  const float* lrp_w     = (const float*)d_in[17];
  const float* nbias     = (const float*)d_in[18];
  const float* ebias     = (const float*)d_in[19];
  const float* lrp_bias  = (const float*)d_in[20];
  const float* nmlp_w1   = (const float*)d_in[21];
  const float* nmlp_b1   = (const float*)d_in[22];
  const float* nmlp_g    = (const float*)d_in[23];
  const float* nmlp_beta = (const float*)d_in[24];
  const float* nmlp_w2   = (const float*)d_in[25];
  const float* nmlp_b2   = (const float*)d_in[26];
  const float* emlp_w1   = (const float*)d_in[27];
  const float* emlp_b1   = (const float*)d_in[28];
  const float* emlp_g    = (const float*)d_in[29];
  const float* emlp_beta = (const float*)d_in[30];
  const float* emlp_w2   = (const float*)d_in[31];
  const float* emlp_b2   = (const float*)d_in[32];

  float* pooled = (float*)d_out;             // 256*128
  float* eoutp  = (float*)d_out + 32768;     // E*128 (second output)

  char* p = (char*)d_ws;
  auto alloc = [&](size_t b) { char* r = p; p += (b + 255) & ~(size_t)255; return r; };
  short* hE   = (short*)alloc((size_t)Ee * 128 * 2);
  short* Qb   = (short*)alloc((size_t)Nn * 256 * 2);
  float* aggR = (float*)alloc((size_t)Nn * 128 * 4);
  float* aggN = (float*)alloc((size_t)Nn * 128 * 4);
  short* hN   = (short*)alloc((size_t)Nn * 128 * 2);
  float* nout = (float*)alloc((size_t)Nn * 128 * 4);
  float* deg  = (float*)alloc((size_t)Nn * 4);
  float* scrE = (float*)alloc((size_t)20000 * 256 * 4);
  float* scrN = (float*)alloc((size_t)313 * 256 * 4);
  float* partE= (float*)alloc((size_t)64 * 256 * 4);
  float* partN= (float*)alloc((size_t)64 * 256 * 4);
  float* stE  = (float*)alloc(256 * 4);
  float* stN  = (float*)alloc(256 * 4);
  short* WA   = (short*)alloc(32768 * 2);
  short* BQ   = (short*)alloc(32768 * 2);
  short* WN   = (short*)alloc(49152 * 2);
  short* W2E  = (short*)alloc(16384 * 2);
  short* W2N  = (short*)alloc(16384 * 2);
  short* WL   = (short*)alloc((size_t)16 * 16384 * 2);
  float* c0e  = (float*)alloc(128 * 4);
  float* c0n  = (float*)alloc(128 * 4);
  int*   cnt  = (int*)alloc((size_t)Nn * 4);
  int*   offA = (int*)alloc((size_t)Nn * 4);
  int*   cur  = (int*)alloc((size_t)Nn * 4);
  int*   order= (int*)alloc((size_t)Ee * 4);
  float* sclE = (float*)alloc((size_t)Ee * 4);

  hipMemsetAsync(deg,  0, (size_t)Nn * 4, stream);
  hipMemsetAsync(cnt,  0, (size_t)Nn * 4, stream);
  hipMemsetAsync(pooled, 0, (size_t)32768 * 4, stream);

  kPrep<<<1601, 256, 0, stream>>>(in_w, out_w, src_w, dst_w, nloop_w, eloop_w, lrp_w,
                                  nbias, ebias, emlp_w1, emlp_b1, nmlp_w1, nmlp_b1,
                                  emlp_w2, nmlp_w2, WA, BQ, WN, W2E, W2N, WL, c0e, c0n);
  kHist<<<Ee / 256, 256, 0, stream>>>(srcI, dstI, cnt, deg);
  kScan<<<1, 256, 0, stream>>>(cnt, offA, cur);
  kScatter<<<Ee / 256, 256, 0, stream>>>(dstI, revI, cur, order, deg, sclE);
  kAgg2<<<Nn / 4, 256, 0, stream>>>(edge_feat, offA, cnt, order, aggR, aggN);
  kQ<<<313, 256, 0, stream>>>(node_feat, BQ, Qb, Nn);
  kN1<<<313, 256, 0, stream>>>(node_feat, aggR, aggN, WN, c0n, hN, scrN, Nn);
  kD<<<20000, 256, 0, stream>>>(edge_feat, WA, Qb, c0e, srcI, dstI, revI, sclE, hE, scrE);
  kRed<<<64, 256, 0, stream>>>(scrE, 20000, partE);
  kRed<<<64, 256, 0, stream>>>(scrN, 313, partN);
  kFin<<<128, 256, 0, stream>>>(partE, (float)Ee, emlp_g, emlp_beta, stE);
  kFin<<<128, 256, 0, stream>>>(partN, (float)Nn, nmlp_g, nmlp_beta, stN);
  kF<<<10000, 256, 0, stream>>>(hE, stE, W2E, emlp_b2, eoutp, Ee);
  kF<<<313, 256, 0, stream>>>(hN, stN, W2N, nmlp_b2, nout, Nn);
  kLRP<<<1252, 256, 0, stream>>>(nout, eoutp, n2pc, n2pv, e2pc, e2pv,
                                 poolr, poolv, WL, lrp_bias, pooled);
}

// Round 10
// 1338.623 us; speedup vs baseline: 1.0791x; 1.0791x over previous
//
#include <hip/hip_runtime.h>
#include <stdint.h>

// Problem constants
constexpr int Nn     = 20000;    // nodes
constexpr int Ee     = 640000;   // edges
constexpr int NPERMc = 20000;    // permutations (R = NPERM*16)

using bf16x8 = __attribute__((ext_vector_type(8))) short;
using f32x4  = __attribute__((ext_vector_type(4))) float;
using s16x4  = __attribute__((ext_vector_type(4))) short;
using u16x8  = __attribute__((ext_vector_type(8))) unsigned short;

__device__ __forceinline__ short f2bf(float f) {
  union { float f; unsigned u; } v; v.f = f;
  unsigned r = v.u + 0x7FFFu + ((v.u >> 16) & 1u);   // RNE
  return (short)(r >> 16);
}
__device__ __forceinline__ float bf2f(unsigned short s) {
  union { unsigned u; float f; } v; v.u = ((unsigned)s) << 16;
  return v.f;
}
__device__ __forceinline__ f32x4 MFMA(bf16x8 a, bf16x8 b, f32x4 c) {
  return __builtin_amdgcn_mfma_f32_16x16x32_bf16(a, b, c, 0, 0, 0);
}

// LDS A-frag swizzle: XOR bits 7-9 of the short-index into bits 3-5.
// Self-consistent (write and read both apply it); preserves 16B alignment
// of b128 reads. Kills the 8-way bank conflict of stage16x128's ds_writes.
__device__ __forceinline__ int swz(int s) { return s ^ (((s >> 7) & 7) << 3); }

// frag-linear layout for B operand (B[k][n]) of 16x16x32:
// lane l holds B[kk*32 + 8*(l/16)+j][t*16 + l%16], stored as
// shorts at ((t*4+kk)*64 + lane)*8 + j  -> conflict-free ds_read_b128
__device__ __forceinline__ int fragIdx(int k, int n) {
  int t = n >> 4, kk = k >> 5;
  int l = ((k & 31) >> 3) * 16 + (n & 15);
  int j = k & 7;
  return ((t * 4 + kk) * 64 + l) * 8 + j;
}

// Stage 16 rows x 128 cols of fp32 into wave-private LDS in A-frag order (bf16).
__device__ __forceinline__ void stage16x128(const float* __restrict__ src, int row0, int M,
                                            int lane, short* lds) {
  #pragma unroll
  for (int it = 0; it < 8; ++it) {
    int u = it * 64 + lane;
    int r = u >> 5;          // row within tile 0..15
    int q = u & 31;          // float4 index within row
    int row = row0 + r;
    float4 v = make_float4(0.f, 0.f, 0.f, 0.f);
    if (row < M) v = ((const float4*)(src + (size_t)row * 128))[q];
    int k  = q * 4;
    int kk = k >> 5;
    int l2 = ((k & 31) >> 3) * 16 + r;
    int j  = k & 7;
    s16x4 s4 = { f2bf(v.x), f2bf(v.y), f2bf(v.z), f2bf(v.w) };
    *(s16x4*)(lds + swz((kk * 64 + l2) * 8 + j)) = s4;
  }
}

// ---------------------------------------------------------------------------
// kPrep: fold all small weight products on-device, emit bf16 frag-order weights
// ---------------------------------------------------------------------------
__global__ __launch_bounds__(256) void kPrep(
    const float* __restrict__ in_w,  const float* __restrict__ out_w,
    const float* __restrict__ src_w, const float* __restrict__ dst_w,
    const float* __restrict__ nloop_w, const float* __restrict__ eloop_w,
    const float* __restrict__ lrp_w,
    const float* __restrict__ nbias, const float* __restrict__ ebias,
    const float* __restrict__ w1e, const float* __restrict__ b1e,
    const float* __restrict__ w1n, const float* __restrict__ b1n,
    const float* __restrict__ w2e, const float* __restrict__ w2n,
    short* __restrict__ WA, short* __restrict__ BQ, short* __restrict__ WN,
    short* __restrict__ W2E, short* __restrict__ W2N, short* __restrict__ WL,
    float* __restrict__ c0e, float* __restrict__ c0n) {
  __shared__ float Rl[16384];          // 64KB: right matrix cached
  int tid = threadIdx.x;
  int blk = blockIdx.x;
  if (blk < 448) {                     // 7 products x 64 blocks
    int p = blk >> 6, sub = blk & 63;
    const float* La; const float* Lb = nullptr; const float* R; short* outp;
    float sOut = 1.f;
    switch (p) {
      case 0: La = eloop_w;             R = w1e; outp = WA;          break;
      case 1: La = src_w; Lb = dst_w;   R = w1e; outp = WA + 16384;  break;
      case 2: La = dst_w;               R = w1e; outp = BQ;          break;
      case 3: La = src_w;               R = w1e; outp = BQ + 16384;  break;
      case 4: La = nloop_w;             R = w1n; outp = WN;          break;
      case 5: La = out_w;               R = w1n; outp = WN + 16384;  break;
      default: La = in_w;               R = w1n; outp = WN + 32768; sOut = -1.f; break;
    }
    for (int i = tid; i < 16384; i += 256) Rl[i] = R[i];
    __syncthreads();
    int e = sub * 256 + tid;
    int k = e >> 7, n = e & 127;
    float acc = 0.f;
    bool hasLb = (Lb != nullptr);
    for (int j = 0; j < 128; ++j) {
      float l = La[k * 128 + j];
      if (hasLb) l -= Lb[k * 128 + j];
      acc += l * Rl[j * 128 + n];
    }
    outp[fragIdx(k, n)] = f2bf(acc * sOut);
  } else if (blk < 512) {              // w2e conversion
    int e = (blk - 448) * 256 + tid; int k = e >> 7, n = e & 127;
    W2E[fragIdx(k, n)] = f2bf(w2e[k * 128 + n]);
  } else if (blk < 576) {              // w2n conversion
    int e = (blk - 512) * 256 + tid; int k = e >> 7, n = e & 127;
    W2N[fragIdx(k, n)] = f2bf(w2n[k * 128 + n]);
  } else if (blk < 1600) {             // lrp_w: 16 a-matrices, B[k=b][n=c] = lrp_w[b][c][a]
    int q = blk - 576; int a = q >> 6;
    int e = (q & 63) * 256 + tid; int k = e >> 7, n = e & 127;
    WL[a * 16384 + fragIdx(k, n)] = f2bf(lrp_w[(k * 128 + n) * 16 + a]);
  } else {                             // c0e = ebias@w1e + b1e ; c0n = nbias@w1n + b1n
    if (tid < 128) {
      float acc = 0.f;
      for (int k2 = 0; k2 < 128; ++k2) acc += ebias[k2] * w1e[k2 * 128 + tid];
      c0e[tid] = acc + b1e[tid];
    } else {
      int n = tid - 128; float acc = 0.f;
      for (int k2 = 0; k2 < 128; ++k2) acc += nbias[k2] * w1n[k2 * 128 + n];
      c0n[n] = acc + b1n[n];
    }
  }
}

// ---------------------------------------------------------------------------
// Aggregation: counting sort by dst, then gather-reduce (no fp32 atomics).
// ---------------------------------------------------------------------------

// kHist: per-dst edge counts (int) + out-degree by src (float, used by kD)
__global__ __launch_bounds__(256) void kHist(
    const int* __restrict__ srcI, const int* __restrict__ dstI,
    int* __restrict__ cnt, float* __restrict__ deg) {
  int e = blockIdx.x * 256 + threadIdx.x;
  atomicAdd(&cnt[dstI[e]], 1);
  atomicAdd(&deg[srcI[e]], 1.0f);
}

// kScan: exclusive prefix sum over Nn bins -> off[] (CSR starts) and cur[] (cursors)
__global__ __launch_bounds__(256) void kScan(const int* __restrict__ cnt,
                                             int* __restrict__ off,
                                             int* __restrict__ cur) {
  __shared__ int lc[Nn];               // 80 KB
  __shared__ int ps[256];
  int tid = threadIdx.x;
  for (int i = tid; i < Nn; i += 256) lc[i] = cnt[i];
  __syncthreads();
  constexpr int CH = (Nn + 255) / 256; // 79 bins per thread
  int base = tid * CH;
  int local = 0;
  for (int i = 0; i < CH; ++i) {
    int idx = base + i;
    if (idx < Nn) local += lc[idx];
  }
  ps[tid] = local;
  __syncthreads();
  for (int d = 1; d < 256; d <<= 1) {  // Hillis-Steele inclusive scan
    int t = (tid >= d) ? ps[tid - d] : 0;
    __syncthreads();
    if (tid >= d) ps[tid] += t;
    __syncthreads();
  }
  int run = ps[tid] - local;           // exclusive prefix at chunk start
  for (int i = 0; i < CH; ++i) {
    int idx = base + i;
    if (idx < Nn) { off[idx] = run; cur[idx] = run; run += lc[idx]; }
  }
}

// kScatter: place edge ids into dst-sorted order; rev flag packed in sign bit.
// Also precompute per-edge degree scale (deg is L2-hot here) so kD reads it
// coalesced instead of doing a random 4B gather in the hot kernel.
__global__ __launch_bounds__(256) void kScatter(
    const int* __restrict__ dstI, const int* __restrict__ revI,
    int* __restrict__ cur, int* __restrict__ order,
    const float* __restrict__ deg, float* __restrict__ sclE) {
  int e = blockIdx.x * 256 + threadIdx.x;
  int d = dstI[e];
  int pos = atomicAdd(&cur[d], 1);
  order[pos] = revI[e] ? (e | (int)0x80000000) : e;
  sclE[e] = 2.0f * (1.0f + log2f(1.0f + deg[d]));
}

// kAgg2: one wave per node; gather 512B edge rows, accumulate in registers.
// (R5-proven unroll-4 float2 form)
__global__ __launch_bounds__(256) void kAgg2(
    const float* __restrict__ ef, const int* __restrict__ off,
    const int* __restrict__ cnt, const int* __restrict__ order,
    float* __restrict__ aggR, float* __restrict__ aggN) {
  int w = threadIdx.x >> 6, lane = threadIdx.x & 63;
  int n = blockIdx.x * 4 + w;
  if (n >= Nn) return;
  int s0 = off[n], c = cnt[n];
  float2 aR = make_float2(0.f, 0.f), aN = make_float2(0.f, 0.f);
  int i = 0;
  for (; i + 3 < c; i += 4) {          // unroll 4: more loads in flight
    int oe0 = order[s0 + i];
    int oe1 = order[s0 + i + 1];
    int oe2 = order[s0 + i + 2];
    int oe3 = order[s0 + i + 3];
    float2 v0 = ((const float2*)(ef + (size_t)(oe0 & 0x7fffffff) * 128))[lane];
    float2 v1 = ((const float2*)(ef + (size_t)(oe1 & 0x7fffffff) * 128))[lane];
    float2 v2 = ((const float2*)(ef + (size_t)(oe2 & 0x7fffffff) * 128))[lane];
    float2 v3 = ((const float2*)(ef + (size_t)(oe3 & 0x7fffffff) * 128))[lane];
    if (oe0 < 0) { aR.x += v0.x; aR.y += v0.y; } else { aN.x += v0.x; aN.y += v0.y; }
    if (oe1 < 0) { aR.x += v1.x; aR.y += v1.y; } else { aN.x += v1.x; aN.y += v1.y; }
    if (oe2 < 0) { aR.x += v2.x; aR.y += v2.y; } else { aN.x += v2.x; aN.y += v2.y; }
    if (oe3 < 0) { aR.x += v3.x; aR.y += v3.y; } else { aN.x += v3.x; aN.y += v3.y; }
  }
  for (; i < c; ++i) {
    int oe = order[s0 + i];
    int e = oe & 0x7fffffff;
    float2 v = ((const float2*)(ef + (size_t)e * 128))[lane];
    if (oe < 0) { aR.x += v.x; aR.y += v.y; } else { aN.x += v.x; aN.y += v.y; }
  }
  ((float2*)(aggR + (size_t)n * 128))[lane] = aR;
  ((float2*)(aggN + (size_t)n * 128))[lane] = aN;
}

// ---------------------------------------------------------------------------
// kQ: Q[n] = nf@(dst_w@w1e) | nf@(src_w@w1e), stored HALF-PERMUTED in BF16:
// Qb[n][h*128 + m*8 + tt] = bf16(Qlogical[n][h*128 + tt*16 + m])
// ---------------------------------------------------------------------------
__global__ __launch_bounds__(256, 2) void kQ(const float* __restrict__ nf,
                                             const short* __restrict__ BQ,
                                             short* __restrict__ Qb, int M) {
  __shared__ __align__(16) short alds[4][2048];
  __shared__ __align__(16) short wbuf[8192];     // 16 tiles x 64 x 8 for current kk
  int tid = threadIdx.x, w = tid >> 6, lane = tid & 63;
  int row0 = blockIdx.x * 64 + w * 16;
  stage16x128(nf, row0, M, lane, alds[w]);
  f32x4 acc[16];
  #pragma unroll
  for (int t = 0; t < 16; ++t) acc[t] = (f32x4){0.f, 0.f, 0.f, 0.f};
  const int4* g4 = (const int4*)BQ;
  for (int kk = 0; kk < 4; ++kk) {
    __syncthreads();
    for (int c = tid; c < 1024; c += 256) {
      int t = c >> 6, l = c & 63;
      ((int4*)wbuf)[c] = g4[(t * 4 + kk) * 64 + l];
    }
    __syncthreads();
    bf16x8 a = *(const bf16x8*)(alds[w] + swz((kk * 64 + lane) * 8));
    #pragma unroll
    for (int t = 0; t < 16; ++t) {
      bf16x8 b = *(const bf16x8*)(wbuf + (t * 64 + lane) * 8);
      acc[t] = MFMA(a, b, acc[t]);
    }
  }
  int sub = lane >> 4, m = lane & 15;
  #pragma unroll
  for (int i = 0; i < 4; ++i) {
    int row = row0 + sub * 4 + i;
    if (row < M) {
      #pragma unroll
      for (int h = 0; h < 2; ++h) {
        bf16x8 pk;
        #pragma unroll
        for (int tt = 0; tt < 8; ++tt) pk[tt] = f2bf(acc[h * 8 + tt][i]);
        *(bf16x8*)(Qb + (size_t)row * 256 + h * 128 + m * 8) = pk;
      }
    }
  }
}

// ---------------------------------------------------------------------------
// kN1: h_n = nf@G1 + aggR@G2 + aggN@G3n + c0n  (K=384), bf16 out (PERMUTED
// layout: hN[row][m*8+t] = h[row][t*16+m]) + BN partials (dense per-block)
// ---------------------------------------------------------------------------
__global__ __launch_bounds__(256, 2) void kN1(
    const float* __restrict__ nf, const float* __restrict__ aggR,
    const float* __restrict__ aggN, const short* __restrict__ WN,
    const float* __restrict__ c0n, short* __restrict__ hN,
    float* __restrict__ scratchN, int M) {
  __shared__ __align__(16) short alds[4][2048];
  __shared__ __align__(16) short wlds[16384];
  __shared__ float statsLDS[256];
  int tid = threadIdx.x, w = tid >> 6, lane = tid & 63;
  int m = lane & 15, sub = lane >> 4;
  statsLDS[tid] = 0.f;
  int row0 = blockIdx.x * 64 + w * 16;
  f32x4 acc[8];
  #pragma unroll
  for (int t = 0; t < 8; ++t) acc[t] = (f32x4){0.f, 0.f, 0.f, 0.f};
  for (int s = 0; s < 3; ++s) {
    const float* src = (s == 0) ? nf : ((s == 1) ? aggR : aggN);
    __syncthreads();
    const int4* g4 = (const int4*)(WN + s * 16384);
    for (int c = tid; c < 2048; c += 256) ((int4*)wlds)[c] = g4[c];
    __syncthreads();
    stage16x128(src, row0, M, lane, alds[w]);
    for (int kk = 0; kk < 4; ++kk) {
      bf16x8 a = *(const bf16x8*)(alds[w] + swz((kk * 64 + lane) * 8));
      #pragma unroll
      for (int t = 0; t < 8; ++t) {
        bf16x8 b = *(const bf16x8*)(wlds + ((t * 4 + kk) * 64 + lane) * 8);
        acc[t] = MFMA(a, b, acc[t]);
      }
    }
  }
  float c0v[8];
  #pragma unroll
  for (int t = 0; t < 8; ++t) c0v[t] = c0n[t * 16 + m];
  float ss[8], sq[8];
  #pragma unroll
  for (int t = 0; t < 8; ++t) { ss[t] = 0.f; sq[t] = 0.f; }
  #pragma unroll
  for (int i = 0; i < 4; ++i) {
    int row = row0 + sub * 4 + i;
    if (row < M) {
      bf16x8 pk;
      #pragma unroll
      for (int t = 0; t < 8; ++t) {
        float h = acc[t][i] + c0v[t];
        pk[t] = f2bf(h); ss[t] += h; sq[t] += h * h;
      }
      *(bf16x8*)(hN + (size_t)row * 128 + m * 8) = pk;
    }
  }
  #pragma unroll
  for (int t = 0; t < 8; ++t) {
    float a = ss[t], b = sq[t];
    a += __shfl_xor(a, 16, 64); b += __shfl_xor(b, 16, 64);
    a += __shfl_xor(a, 32, 64); b += __shfl_xor(b, 32, 64);
    if (lane < 16) {
      atomicAdd(&statsLDS[t * 16 + lane], a);
      atomicAdd(&statsLDS[128 + t * 16 + lane], b);
    }
  }
  __syncthreads();
  scratchN[(size_t)blockIdx.x * 256 + tid] = statsLDS[tid];   // dense 1KB/block
}

// ---------------------------------------------------------------------------
// kD: h_e = ef@A1 + scl*(ef@A2) + edge_msg-gather(Qb bf16) + c0e ; BN stats
// R10: exact R7 structure (16 rows/wave, grid 10000, epilogue Q gather,
// 16B hE stores) + wbuf staging via global_load_lds (async direct-to-LDS,
// no VGPR round-trip; drained by the s_waitcnt vmcnt(0) of __syncthreads).
// ---------------------------------------------------------------------------
__global__ __launch_bounds__(256, 4) void kD(
    const float* __restrict__ ef, const short* __restrict__ WA,
    const short* __restrict__ Qb, const float* __restrict__ c0e,
    const int* __restrict__ srcI, const int* __restrict__ dstI,
    const int* __restrict__ revI, const float* __restrict__ sclE,
    short* __restrict__ hE, float* __restrict__ scratchE) {
  __shared__ __align__(16) short alds[4][2048];   // 16 rows per wave
  __shared__ __align__(16) short wbuf[8192];      // both matrices, one kk slice
  __shared__ float statsLDS[256];
  int tid = threadIdx.x, w = tid >> 6, lane = tid & 63;
  int m = lane & 15, sub = lane >> 4;
  statsLDS[tid] = 0.f;
  int row0 = blockIdx.x * 64 + w * 16;
  // prefetch per-edge index data; Q gathered in epilogue (TLP-hidden)
  float scl[4]; int qa[4], qb[4];
  #pragma unroll
  for (int i = 0; i < 4; ++i) {
    int e = row0 + sub * 4 + i;
    int s_ = srcI[e], d_ = dstI[e], r_ = revI[e];
    scl[i] = sclE[e];
    int na = r_ ? s_ : d_;
    int nb = r_ ? d_ : s_;
    qa[i] = na * 256 + m * 8;
    qb[i] = nb * 256 + 128 + m * 8;
  }
  stage16x128(ef, row0, Ee, lane, alds[w]);
  f32x4 acc1[8], acc2[8];
  #pragma unroll
  for (int t = 0; t < 8; ++t) { acc1[t] = (f32x4){0,0,0,0}; acc2[t] = (f32x4){0,0,0,0}; }
  const int4* g4 = (const int4*)WA;
  for (int kk = 0; kk < 4; ++kk) {
    __syncthreads();                   // wbuf free (also drains prior reads)
    #pragma unroll
    for (int it = 0; it < 4; ++it) {
      int c = it * 256 + tid;          // dest int4 index; (c & 63) == lane
      int mm = c >> 9, t = (c >> 6) & 7;
      __builtin_amdgcn_global_load_lds(
          (const __attribute__((address_space(1))) unsigned int*)
              (g4 + (mm * 2048 + (t * 4 + kk) * 64 + (c & 63))),
          (__attribute__((address_space(3))) unsigned int*)
              (((int4*)wbuf) + (it * 256 + w * 64)),   // wave-uniform base
          16, 0, 0);
    }
    __syncthreads();                   // s_waitcnt vmcnt(0) drains the DMA
    bf16x8 a = *(const bf16x8*)(alds[w] + swz((kk * 64 + lane) * 8));
    #pragma unroll
    for (int t = 0; t < 8; ++t) {
      bf16x8 b1 = *(const bf16x8*)(wbuf + (t * 64 + lane) * 8);
      bf16x8 b2 = *(const bf16x8*)(wbuf + 4096 + (t * 64 + lane) * 8);
      acc1[t] = MFMA(a, b1, acc1[t]);
      acc2[t] = MFMA(a, b2, acc2[t]);
    }
  }
  float c0v[8];
  #pragma unroll
  for (int t = 0; t < 8; ++t) c0v[t] = c0e[t * 16 + m];
  float ss[8], sq[8];
  #pragma unroll
  for (int t = 0; t < 8; ++t) { ss[t] = 0.f; sq[t] = 0.f; }
  #pragma unroll
  for (int i = 0; i < 4; ++i) {
    int e = row0 + sub * 4 + i;
    u16x8 A = *(const u16x8*)(Qb + qa[i]);
    u16x8 B = *(const u16x8*)(Qb + qb[i]);
    bf16x8 pk;
    #pragma unroll
    for (int t = 0; t < 8; ++t) {
      float qv = bf2f(A[t]) - bf2f(B[t]);
      float h = acc1[t][i] + scl[i] * acc2[t][i] + qv + c0v[t];
      pk[t] = f2bf(h);
      ss[t] += h; sq[t] += h * h;
    }
    *(bf16x8*)(hE + (size_t)e * 128 + m * 8) = pk;   // permuted: [m*8+t]
  }
  #pragma unroll
  for (int t = 0; t < 8; ++t) {
    float a = ss[t], b = sq[t];
    a += __shfl_xor(a, 16, 64); b += __shfl_xor(b, 16, 64);
    a += __shfl_xor(a, 32, 64); b += __shfl_xor(b, 32, 64);
    if (lane < 16) {
      atomicAdd(&statsLDS[t * 16 + lane], a);
      atomicAdd(&statsLDS[128 + t * 16 + lane], b);
    }
  }
  __syncthreads();
  scratchE[(size_t)blockIdx.x * 256 + tid] = statsLDS[tid];   // dense 1KB/block
}

// ---------------------------------------------------------------------------
// kRed: stage-1 reduce of dense per-block stats [NB][256] -> part [64][256]
// ---------------------------------------------------------------------------
__global__ __launch_bounds__(256) void kRed(const float* __restrict__ scr, int NB,
                                            float* __restrict__ part) {
  int tid = threadIdx.x, b = blockIdx.x;
  float acc = 0.f;
  for (int r = b; r < NB; r += 64)
    acc += scr[(size_t)r * 256 + tid];
  part[b * 256 + tid] = acc;
}

// ---------------------------------------------------------------------------
// kFin: reduce part[64][256] -> s = g*rsqrt(var+eps), t = beta - mu*s
// ---------------------------------------------------------------------------
__global__ __launch_bounds__(256) void kFin(const float* __restrict__ part,
                                            float M, const float* __restrict__ g,
                                            const float* __restrict__ beta,
                                            float* __restrict__ st) {
  __shared__ float red[256];
  __shared__ float red2[256];
  int c = blockIdx.x;     // 0..127
  int tid = threadIdx.x;
  float s = 0.f, q = 0.f;
  if (tid < 64) {
    s = part[tid * 256 + c];
    q = part[tid * 256 + 128 + c];
  }
  red[tid] = s; red2[tid] = q;
  __syncthreads();
  for (int off = 32; off > 0; off >>= 1) {
    if (tid < off) { red[tid] += red[tid + off]; red2[tid] += red2[tid + off]; }
    __syncthreads();
  }
  if (tid == 0) {
    float mu  = red[0] / M;
    float var = red2[0] / M - mu * mu;
    float inv = rsqrtf(var + 1e-5f);
    float sc  = g[c] * inv;
    st[c] = sc;
    st[128 + c] = beta[c] - mu * sc;
  }
}

// ---------------------------------------------------------------------------
// kF: out = relu(h*s + t) @ w2 + b2     (h is in PERMUTED layout [m*8+t])
// w2 staged in 8KB per-kk slices -> LDS 24KB -> 6 blocks/CU.
// ---------------------------------------------------------------------------
__global__ __launch_bounds__(256, 6) void kF(const short* __restrict__ h,
                                             const float* __restrict__ st,
                                             const short* __restrict__ w2f,
                                             const float* __restrict__ b2,
                                             float* __restrict__ outp, int M) {
  __shared__ __align__(16) short alds[4][2048];
  __shared__ __align__(16) short wbuf[4096];    // one kk slice: 8 tiles
  int tid = threadIdx.x, w = tid >> 6, lane = tid & 63;
  int m2 = lane & 15;
  int row0 = blockIdx.x * 64 + w * 16;
  float sc8[8], tb8[8];
  #pragma unroll
  for (int q = 0; q < 8; ++q) {
    int col = q * 16 + m2;
    sc8[q] = st[col]; tb8[q] = st[128 + col];
  }
  #pragma unroll
  for (int it = 0; it < 4; ++it) {
    int r = it * 4 + (lane >> 4);
    int row = row0 + r;
    u16x8 hv = {0, 0, 0, 0, 0, 0, 0, 0};
    if (row < M) hv = *(const u16x8*)(h + (size_t)row * 128 + m2 * 8);
    #pragma unroll
    for (int q = 0; q < 8; ++q) {
      float f = bf2f(hv[q]);
      float v = fmaxf(f * sc8[q] + tb8[q], 0.f);
      int k = q * 16 + m2;
      int kk = k >> 5, l2 = ((k & 31) >> 3) * 16 + r, j = k & 7;
      alds[w][swz((kk * 64 + l2) * 8 + j)] = f2bf(v);
    }
  }
  f32x4 acc[8];
  #pragma unroll
  for (int t = 0; t < 8; ++t) acc[t] = (f32x4){0.f, 0.f, 0.f, 0.f};
  const int4* g4w = (const int4*)w2f;
  for (int kk = 0; kk < 4; ++kk) {
    __syncthreads();
    for (int c = tid; c < 512; c += 256) {
      int t = c >> 6, l = c & 63;
      ((int4*)wbuf)[c] = g4w[(t * 4 + kk) * 64 + l];
    }
    __syncthreads();
    bf16x8 a = *(const bf16x8*)(alds[w] + swz((kk * 64 + lane) * 8));
    #pragma unroll
    for (int t = 0; t < 8; ++t) {
      bf16x8 b = *(const bf16x8*)(wbuf + (t * 64 + lane) * 8);
      acc[t] = MFMA(a, b, acc[t]);
    }
  }
  int sub = lane >> 4;
  #pragma unroll
  for (int t = 0; t < 8; ++t) {
    int col = t * 16 + (lane & 15);
    float bb = b2[col];
    #pragma unroll
    for (int i = 0; i < 4; ++i) {
      int row = row0 + sub * 4 + i;
      if (row < M) outp[(size_t)row * 128 + col] = acc[t][i] + bb;
    }
  }
}

// ---------------------------------------------------------------------------
// kLRP: perm gather -> K=2048 GEMM over 4 of 16 a-matrices per block
// (a-split x4, grid 313*4, R5-proven form: 16KB monolithic wlds per a)
// ---------------------------------------------------------------------------
__global__ __launch_bounds__(256, 2) void kLRP(
    const float* __restrict__ nout, const float* __restrict__ eoutp,
    const int* __restrict__ n2pc, const float* __restrict__ n2pv,
    const int* __restrict__ e2pc, const float* __restrict__ e2pv,
    const int* __restrict__ poolr, const float* __restrict__ poolv,
    const short* __restrict__ WL, const float* __restrict__ lrp_bias,
    float* __restrict__ pooled) {
  __shared__ __align__(16) short alds[4][2048];
  __shared__ __align__(16) short wlds[16384];
  int tid = threadIdx.x, w = tid >> 6, lane = tid & 63;
  int blk = blockIdx.x % 313, g = blockIdx.x / 313;  // g in 0..3
  int row0 = blk * 64 + w * 16;
  int a0 = g * 4;
  f32x4 acc[8];
  #pragma unroll
  for (int t = 0; t < 8; ++t) acc[t] = (f32x4){0.f, 0.f, 0.f, 0.f};
  for (int a = a0; a < a0 + 4; ++a) {
    __syncthreads();
    const int4* g4 = (const int4*)(WL + a * 16384);
    for (int c = tid; c < 2048; c += 256) ((int4*)wlds)[c] = g4[c];
    __syncthreads();
    #pragma unroll
    for (int it = 0; it < 8; ++it) {
      int u = it * 64 + lane;
      int r = u >> 5;
      int q = u & 31;
      int d = row0 + r;
      float4 v = make_float4(0.f, 0.f, 0.f, 0.f);
      if (d < NPERMc) {
        int i = d * 16 + a;
        int nc = n2pc[i]; float nv = n2pv[i];
        int ec = e2pc[i]; float ev = e2pv[i];
        float4 nr = ((const float4*)(nout  + (size_t)nc * 128))[q];
        float4 er = ((const float4*)(eoutp + (size_t)ec * 128))[q];
        v.x = nv * nr.x + ev * er.x;
        v.y = nv * nr.y + ev * er.y;
        v.z = nv * nr.z + ev * er.z;
        v.w = nv * nr.w + ev * er.w;
      }
      int k  = q * 4;
      int kk = k >> 5;
      int l2 = ((k & 31) >> 3) * 16 + r;
      int j  = k & 7;
      s16x4 s4 = { f2bf(v.x), f2bf(v.y), f2bf(v.z), f2bf(v.w) };
      *(s16x4*)(alds[w] + swz((kk * 64 + l2) * 8 + j)) = s4;
    }
    for (int kk = 0; kk < 4; ++kk) {
      bf16x8 aa = *(const bf16x8*)(alds[w] + swz((kk * 64 + lane) * 8));
      #pragma unroll
      for (int t = 0; t < 8; ++t) {
        bf16x8 b = *(const bf16x8*)(wlds + ((t * 4 + kk) * 64 + lane) * 8);
        acc[t] = MFMA(aa, b, acc[t]);
      }
    }
  }
  int sub = lane >> 4;
  #pragma unroll
  for (int t = 0; t < 8; ++t) {
    int col = t * 16 + (lane & 15);
    float lb = (g == 0) ? lrp_bias[col] : 0.f;
    #pragma unroll
    for (int i = 0; i < 4; ++i) {
      int d = row0 + sub * 4 + i;
      if (d < NPERMc) {
        float val = acc[t][i] + lb;
        atomicAdd(&pooled[poolr[d] * 128 + col], poolv[d] * val);
      }
    }
  }
}

// ---------------------------------------------------------------------------
extern "C" void kernel_launch(void* const* d_in, const int* in_sizes, int n_in,
                              void* d_out, int out_size, void* d_ws, size_t ws_size,
                              hipStream_t stream) {
  (void)in_sizes; (void)n_in; (void)out_size; (void)ws_size;
  const float* node_feat = (const float*)d_in[0];
  const float* edge_feat = (const float*)d_in[1];
  const int*   srcI      = (const int*)d_in[2];
  const int*   dstI      = (const int*)d_in[3];
  const int*   revI      = (const int*)d_in[4];
  const int*   n2pc      = (const int*)d_in[5];
  const float* n2pv      = (const float*)d_in[6];
  const int*   e2pc      = (const int*)d_in[7];
  const float* e2pv      = (const float*)d_in[8];
  const int*   poolr     = (const int*)d_in[9];
  const float* poolv     = (const float*)d_in[10];
  const float* in_w      = (const float*)d_in[11];
  const float* out_w     = (const float*)d_in[12];
  const float* src_w     = (const float*)d_in[13];
  const float* dst_w     = (const float*)d_in[14];
  const float* nloop_w   = (const float*)d_in[15];
  const float* eloop_w   = (const float*)d_in[16];
  const float* lrp_w     = (const float*)d_in[17];
  const float* nbias     = (const float*)d_in[18];
  const float* ebias     = (const float*)d_in[19];
  const float* lrp_bias  = (const float*)d_in[20];
  const float* nmlp_w1   = (const float*)d_in[21];
  const float* nmlp_b1   = (const float*)d_in[22];
  const float* nmlp_g    = (const float*)d_in[23];
  const float* nmlp_beta = (const float*)d_in[24];
  const float* nmlp_w2   = (const float*)d_in[25];
  const float* nmlp_b2   = (const float*)d_in[26];
  const float* emlp_w1   = (const float*)d_in[27];
  const float* emlp_b1   = (const float*)d_in[28];
  const float* emlp_g    = (const float*)d_in[29];
  const float* emlp_beta = (const float*)d_in[30];
  const float* emlp_w2   = (const float*)d_in[31];
  const float* emlp_b2   = (const float*)d_in[32];

  float* pooled = (float*)d_out;             // 256*128
  float* eoutp  = (float*)d_out + 32768;     // E*128 (second output)

  char* p = (char*)d_ws;
  auto alloc = [&](size_t b) { char* r = p; p += (b + 255) & ~(size_t)255; return r; };
  short* hE   = (short*)alloc((size_t)Ee * 128 * 2);
  short* Qb   = (short*)alloc((size_t)Nn * 256 * 2);
  float* aggR = (float*)alloc((size_t)Nn * 128 * 4);
  float* aggN = (float*)alloc((size_t)Nn * 128 * 4);
  short* hN   = (short*)alloc((size_t)Nn * 128 * 2);
  float* nout = (float*)alloc((size_t)Nn * 128 * 4);
  float* deg  = (float*)alloc((size_t)Nn * 4);
  float* scrE = (float*)alloc((size_t)10000 * 256 * 4);
  float* scrN = (float*)alloc((size_t)313 * 256 * 4);
  float* partE= (float*)alloc((size_t)64 * 256 * 4);
  float* partN= (float*)alloc((size_t)64 * 256 * 4);
  float* stE  = (float*)alloc(256 * 4);
  float* stN  = (float*)alloc(256 * 4);
  short* WA   = (short*)alloc(32768 * 2);
  short* BQ   = (short*)alloc(32768 * 2);
  short* WN   = (short*)alloc(49152 * 2);
  short* W2E  = (short*)alloc(16384 * 2);
  short* W2N  = (short*)alloc(16384 * 2);
  short* WL   = (short*)alloc((size_t)16 * 16384 * 2);
  float* c0e  = (float*)alloc(128 * 4);
  float* c0n  = (float*)alloc(128 * 4);
  int*   cnt  = (int*)alloc((size_t)Nn * 4);
  int*   offA = (int*)alloc((size_t)Nn * 4);
  int*   cur  = (int*)alloc((size_t)Nn * 4);
  int*   order= (int*)alloc((size_t)Ee * 4);
  float* sclE = (float*)alloc((size_t)Ee * 4);

  hipMemsetAsync(deg,  0, (size_t)Nn * 4, stream);
  hipMemsetAsync(cnt,  0, (size_t)Nn * 4, stream);
  hipMemsetAsync(pooled, 0, (size_t)32768 * 4, stream);

  kPrep<<<1601, 256, 0, stream>>>(in_w, out_w, src_w, dst_w, nloop_w, eloop_w, lrp_w,
                                  nbias, ebias, emlp_w1, emlp_b1, nmlp_w1, nmlp_b1,
                                  emlp_w2, nmlp_w2, WA, BQ, WN, W2E, W2N, WL, c0e, c0n);
  kHist<<<Ee / 256, 256, 0, stream>>>(srcI, dstI, cnt, deg);
  kScan<<<1, 256, 0, stream>>>(cnt, offA, cur);
  kScatter<<<Ee / 256, 256, 0, stream>>>(dstI, revI, cur, order, deg, sclE);
  kAgg2<<<Nn / 4, 256, 0, stream>>>(edge_feat, offA, cnt, order, aggR, aggN);
  kQ<<<313, 256, 0, stream>>>(node_feat, BQ, Qb, Nn);
  kN1<<<313, 256, 0, stream>>>(node_feat, aggR, aggN, WN, c0n, hN, scrN, Nn);
  kD<<<10000, 256, 0, stream>>>(edge_feat, WA, Qb, c0e, srcI, dstI, revI, sclE, hE, scrE);
  kRed<<<64, 256, 0, stream>>>(scrE, 10000, partE);
  kRed<<<64, 256, 0, stream>>>(scrN, 313, partN);
  kFin<<<128, 256, 0, stream>>>(partE, (float)Ee, emlp_g, emlp_beta, stE);
  kFin<<<128, 256, 0, stream>>>(partN, (float)Nn, nmlp_g, nmlp_beta, stN);
  kF<<<10000, 256, 0, stream>>>(hE, stE, W2E, emlp_b2, eoutp, Ee);
  kF<<<313, 256, 0, stream>>>(hN, stN, W2N, nmlp_b2, nout, Nn);
  kLRP<<<1252, 256, 0, stream>>>(nout, eoutp, n2pc, n2pv, e2pc, e2pv,
                                 poolr, poolv, WL, lrp_bias, pooled);
}

// Round 11
// 1299.707 us; speedup vs baseline: 1.1114x; 1.0299x over previous
//
#include <hip/hip_runtime.h>
#include <stdint.h>

// Problem constants
constexpr int Nn     = 20000;    // nodes
constexpr int Ee     = 640000;   // edges
constexpr int NPERMc = 20000;    // permutations (R = NPERM*16)

using bf16x8 = __attribute__((ext_vector_type(8))) short;
using f32x4  = __attribute__((ext_vector_type(4))) float;
using s16x4  = __attribute__((ext_vector_type(4))) short;
using u16x8  = __attribute__((ext_vector_type(8))) unsigned short;

__device__ __forceinline__ short f2bf(float f) {
  union { float f; unsigned u; } v; v.f = f;
  unsigned r = v.u + 0x7FFFu + ((v.u >> 16) & 1u);   // RNE
  return (short)(r >> 16);
}
__device__ __forceinline__ float bf2f(unsigned short s) {
  union { unsigned u; float f; } v; v.u = ((unsigned)s) << 16;
  return v.f;
}
__device__ __forceinline__ f32x4 MFMA(bf16x8 a, bf16x8 b, f32x4 c) {
  return __builtin_amdgcn_mfma_f32_16x16x32_bf16(a, b, c, 0, 0, 0);
}

// LDS A-frag swizzle: XOR bits 7-9 of the short-index into bits 3-5.
// Self-consistent (write and read both apply it); preserves 16B alignment
// of b128 reads. Kills the 8-way bank conflict of stage16x128's ds_writes.
__device__ __forceinline__ int swz(int s) { return s ^ (((s >> 7) & 7) << 3); }

// frag-linear layout for B operand (B[k][n]) of 16x16x32:
// lane l holds B[kk*32 + 8*(l/16)+j][t*16 + l%16], stored as
// shorts at ((t*4+kk)*64 + lane)*8 + j  -> conflict-free ds_read_b128
__device__ __forceinline__ int fragIdx(int k, int n) {
  int t = n >> 4, kk = k >> 5;
  int l = ((k & 31) >> 3) * 16 + (n & 15);
  int j = k & 7;
  return ((t * 4 + kk) * 64 + l) * 8 + j;
}

// Stage 16 rows x 128 cols of fp32 into wave-private LDS in A-frag order (bf16).
__device__ __forceinline__ void stage16x128(const float* __restrict__ src, int row0, int M,
                                            int lane, short* lds) {
  #pragma unroll
  for (int it = 0; it < 8; ++it) {
    int u = it * 64 + lane;
    int r = u >> 5;          // row within tile 0..15
    int q = u & 31;          // float4 index within row
    int row = row0 + r;
    float4 v = make_float4(0.f, 0.f, 0.f, 0.f);
    if (row < M) v = ((const float4*)(src + (size_t)row * 128))[q];
    int k  = q * 4;
    int kk = k >> 5;
    int l2 = ((k & 31) >> 3) * 16 + r;
    int j  = k & 7;
    s16x4 s4 = { f2bf(v.x), f2bf(v.y), f2bf(v.z), f2bf(v.w) };
    *(s16x4*)(lds + swz((kk * 64 + l2) * 8 + j)) = s4;
  }
}

// ---------------------------------------------------------------------------
// kPrep: fold all small weight products on-device, emit bf16 frag-order weights
// ---------------------------------------------------------------------------
__global__ __launch_bounds__(256) void kPrep(
    const float* __restrict__ in_w,  const float* __restrict__ out_w,
    const float* __restrict__ src_w, const float* __restrict__ dst_w,
    const float* __restrict__ nloop_w, const float* __restrict__ eloop_w,
    const float* __restrict__ lrp_w,
    const float* __restrict__ nbias, const float* __restrict__ ebias,
    const float* __restrict__ w1e, const float* __restrict__ b1e,
    const float* __restrict__ w1n, const float* __restrict__ b1n,
    const float* __restrict__ w2e, const float* __restrict__ w2n,
    short* __restrict__ WA, short* __restrict__ BQ, short* __restrict__ WN,
    short* __restrict__ W2E, short* __restrict__ W2N, short* __restrict__ WL,
    float* __restrict__ c0e, float* __restrict__ c0n) {
  __shared__ float Rl[16384];          // 64KB: right matrix cached
  int tid = threadIdx.x;
  int blk = blockIdx.x;
  if (blk < 448) {                     // 7 products x 64 blocks
    int p = blk >> 6, sub = blk & 63;
    const float* La; const float* Lb = nullptr; const float* R; short* outp;
    float sOut = 1.f;
    switch (p) {
      case 0: La = eloop_w;             R = w1e; outp = WA;          break;
      case 1: La = src_w; Lb = dst_w;   R = w1e; outp = WA + 16384;  break;
      case 2: La = dst_w;               R = w1e; outp = BQ;          break;
      case 3: La = src_w;               R = w1e; outp = BQ + 16384;  break;
      case 4: La = nloop_w;             R = w1n; outp = WN;          break;
      case 5: La = out_w;               R = w1n; outp = WN + 16384;  break;
      default: La = in_w;               R = w1n; outp = WN + 32768; sOut = -1.f; break;
    }
    for (int i = tid; i < 16384; i += 256) Rl[i] = R[i];
    __syncthreads();
    int e = sub * 256 + tid;
    int k = e >> 7, n = e & 127;
    float acc = 0.f;
    bool hasLb = (Lb != nullptr);
    for (int j = 0; j < 128; ++j) {
      float l = La[k * 128 + j];
      if (hasLb) l -= Lb[k * 128 + j];
      acc += l * Rl[j * 128 + n];
    }
    outp[fragIdx(k, n)] = f2bf(acc * sOut);
  } else if (blk < 512) {              // w2e conversion
    int e = (blk - 448) * 256 + tid; int k = e >> 7, n = e & 127;
    W2E[fragIdx(k, n)] = f2bf(w2e[k * 128 + n]);
  } else if (blk < 576) {              // w2n conversion
    int e = (blk - 512) * 256 + tid; int k = e >> 7, n = e & 127;
    W2N[fragIdx(k, n)] = f2bf(w2n[k * 128 + n]);
  } else if (blk < 1600) {             // lrp_w: 16 a-matrices, B[k=b][n=c] = lrp_w[b][c][a]
    int q = blk - 576; int a = q >> 6;
    int e = (q & 63) * 256 + tid; int k = e >> 7, n = e & 127;
    WL[a * 16384 + fragIdx(k, n)] = f2bf(lrp_w[(k * 128 + n) * 16 + a]);
  } else {                             // c0e = ebias@w1e + b1e ; c0n = nbias@w1n + b1n
    if (tid < 128) {
      float acc = 0.f;
      for (int k2 = 0; k2 < 128; ++k2) acc += ebias[k2] * w1e[k2 * 128 + tid];
      c0e[tid] = acc + b1e[tid];
    } else {
      int n = tid - 128; float acc = 0.f;
      for (int k2 = 0; k2 < 128; ++k2) acc += nbias[k2] * w1n[k2 * 128 + n];
      c0n[n] = acc + b1n[n];
    }
  }
}

// ---------------------------------------------------------------------------
// Aggregation: counting sort by dst, then gather-reduce (no fp32 atomics).
// ---------------------------------------------------------------------------

// kHist: per-dst edge counts (int) + out-degree by src (float, used by kD)
__global__ __launch_bounds__(256) void kHist(
    const int* __restrict__ srcI, const int* __restrict__ dstI,
    int* __restrict__ cnt, float* __restrict__ deg) {
  int e = blockIdx.x * 256 + threadIdx.x;
  atomicAdd(&cnt[dstI[e]], 1);
  atomicAdd(&deg[srcI[e]], 1.0f);
}

// kScan: exclusive prefix sum over Nn bins -> off[] (CSR starts) and cur[] (cursors)
__global__ __launch_bounds__(256) void kScan(const int* __restrict__ cnt,
                                             int* __restrict__ off,
                                             int* __restrict__ cur) {
  __shared__ int lc[Nn];               // 80 KB
  __shared__ int ps[256];
  int tid = threadIdx.x;
  for (int i = tid; i < Nn; i += 256) lc[i] = cnt[i];
  __syncthreads();
  constexpr int CH = (Nn + 255) / 256; // 79 bins per thread
  int base = tid * CH;
  int local = 0;
  for (int i = 0; i < CH; ++i) {
    int idx = base + i;
    if (idx < Nn) local += lc[idx];
  }
  ps[tid] = local;
  __syncthreads();
  for (int d = 1; d < 256; d <<= 1) {  // Hillis-Steele inclusive scan
    int t = (tid >= d) ? ps[tid - d] : 0;
    __syncthreads();
    if (tid >= d) ps[tid] += t;
    __syncthreads();
  }
  int run = ps[tid] - local;           // exclusive prefix at chunk start
  for (int i = 0; i < CH; ++i) {
    int idx = base + i;
    if (idx < Nn) { off[idx] = run; cur[idx] = run; run += lc[idx]; }
  }
}

// kScatter: place edge ids into dst-sorted order; rev flag packed in sign bit.
// Also precompute per-edge degree scale (deg is L2-hot here) so kD reads it
// coalesced instead of doing a random 4B gather in the hot kernel.
__global__ __launch_bounds__(256) void kScatter(
    const int* __restrict__ dstI, const int* __restrict__ revI,
    int* __restrict__ cur, int* __restrict__ order,
    const float* __restrict__ deg, float* __restrict__ sclE) {
  int e = blockIdx.x * 256 + threadIdx.x;
  int d = dstI[e];
  int pos = atomicAdd(&cur[d], 1);
  order[pos] = revI[e] ? (e | (int)0x80000000) : e;
  sclE[e] = 2.0f * (1.0f + log2f(1.0f + deg[d]));
}

// kAgg2: one wave per node; gather 512B edge rows, accumulate in registers.
// (R5-proven unroll-4 float2 form)
__global__ __launch_bounds__(256) void kAgg2(
    const float* __restrict__ ef, const int* __restrict__ off,
    const int* __restrict__ cnt, const int* __restrict__ order,
    float* __restrict__ aggR, float* __restrict__ aggN) {
  int w = threadIdx.x >> 6, lane = threadIdx.x & 63;
  int n = blockIdx.x * 4 + w;
  if (n >= Nn) return;
  int s0 = off[n], c = cnt[n];
  float2 aR = make_float2(0.f, 0.f), aN = make_float2(0.f, 0.f);
  int i = 0;
  for (; i + 3 < c; i += 4) {          // unroll 4: more loads in flight
    int oe0 = order[s0 + i];
    int oe1 = order[s0 + i + 1];
    int oe2 = order[s0 + i + 2];
    int oe3 = order[s0 + i + 3];
    float2 v0 = ((const float2*)(ef + (size_t)(oe0 & 0x7fffffff) * 128))[lane];
    float2 v1 = ((const float2*)(ef + (size_t)(oe1 & 0x7fffffff) * 128))[lane];
    float2 v2 = ((const float2*)(ef + (size_t)(oe2 & 0x7fffffff) * 128))[lane];
    float2 v3 = ((const float2*)(ef + (size_t)(oe3 & 0x7fffffff) * 128))[lane];
    if (oe0 < 0) { aR.x += v0.x; aR.y += v0.y; } else { aN.x += v0.x; aN.y += v0.y; }
    if (oe1 < 0) { aR.x += v1.x; aR.y += v1.y; } else { aN.x += v1.x; aN.y += v1.y; }
    if (oe2 < 0) { aR.x += v2.x; aR.y += v2.y; } else { aN.x += v2.x; aN.y += v2.y; }
    if (oe3 < 0) { aR.x += v3.x; aR.y += v3.y; } else { aN.x += v3.x; aN.y += v3.y; }
  }
  for (; i < c; ++i) {
    int oe = order[s0 + i];
    int e = oe & 0x7fffffff;
    float2 v = ((const float2*)(ef + (size_t)e * 128))[lane];
    if (oe < 0) { aR.x += v.x; aR.y += v.y; } else { aN.x += v.x; aN.y += v.y; }
  }
  ((float2*)(aggR + (size_t)n * 128))[lane] = aR;
  ((float2*)(aggN + (size_t)n * 128))[lane] = aN;
}

// ---------------------------------------------------------------------------
// kQ: Q[n] = nf@(dst_w@w1e) | nf@(src_w@w1e), stored HALF-PERMUTED in BF16:
// Qb[n][h*128 + m*8 + tt] = bf16(Qlogical[n][h*128 + tt*16 + m])
// ---------------------------------------------------------------------------
__global__ __launch_bounds__(256, 2) void kQ(const float* __restrict__ nf,
                                             const short* __restrict__ BQ,
                                             short* __restrict__ Qb, int M) {
  __shared__ __align__(16) short alds[4][2048];
  __shared__ __align__(16) short wbuf[8192];     // 16 tiles x 64 x 8 for current kk
  int tid = threadIdx.x, w = tid >> 6, lane = tid & 63;
  int row0 = blockIdx.x * 64 + w * 16;
  stage16x128(nf, row0, M, lane, alds[w]);
  f32x4 acc[16];
  #pragma unroll
  for (int t = 0; t < 16; ++t) acc[t] = (f32x4){0.f, 0.f, 0.f, 0.f};
  const int4* g4 = (const int4*)BQ;
  for (int kk = 0; kk < 4; ++kk) {
    __syncthreads();
    for (int c = tid; c < 1024; c += 256) {
      int t = c >> 6, l = c & 63;
      ((int4*)wbuf)[c] = g4[(t * 4 + kk) * 64 + l];
    }
    __syncthreads();
    bf16x8 a = *(const bf16x8*)(alds[w] + swz((kk * 64 + lane) * 8));
    #pragma unroll
    for (int t = 0; t < 16; ++t) {
      bf16x8 b = *(const bf16x8*)(wbuf + (t * 64 + lane) * 8);
      acc[t] = MFMA(a, b, acc[t]);
    }
  }
  int sub = lane >> 4, m = lane & 15;
  #pragma unroll
  for (int i = 0; i < 4; ++i) {
    int row = row0 + sub * 4 + i;
    if (row < M) {
      #pragma unroll
      for (int h = 0; h < 2; ++h) {
        bf16x8 pk;
        #pragma unroll
        for (int tt = 0; tt < 8; ++tt) pk[tt] = f2bf(acc[h * 8 + tt][i]);
        *(bf16x8*)(Qb + (size_t)row * 256 + h * 128 + m * 8) = pk;
      }
    }
  }
}

// ---------------------------------------------------------------------------
// kN1: h_n = nf@G1 + aggR@G2 + aggN@G3n + c0n  (K=384), bf16 out (PERMUTED
// layout: hN[row][m*8+t] = h[row][t*16+m]) + BN partials (dense per-block)
// ---------------------------------------------------------------------------
__global__ __launch_bounds__(256, 2) void kN1(
    const float* __restrict__ nf, const float* __restrict__ aggR,
    const float* __restrict__ aggN, const short* __restrict__ WN,
    const float* __restrict__ c0n, short* __restrict__ hN,
    float* __restrict__ scratchN, int M) {
  __shared__ __align__(16) short alds[4][2048];
  __shared__ __align__(16) short wlds[16384];
  __shared__ float statsLDS[256];
  int tid = threadIdx.x, w = tid >> 6, lane = tid & 63;
  int m = lane & 15, sub = lane >> 4;
  statsLDS[tid] = 0.f;
  int row0 = blockIdx.x * 64 + w * 16;
  f32x4 acc[8];
  #pragma unroll
  for (int t = 0; t < 8; ++t) acc[t] = (f32x4){0.f, 0.f, 0.f, 0.f};
  for (int s = 0; s < 3; ++s) {
    const float* src = (s == 0) ? nf : ((s == 1) ? aggR : aggN);
    __syncthreads();
    const int4* g4 = (const int4*)(WN + s * 16384);
    for (int c = tid; c < 2048; c += 256) ((int4*)wlds)[c] = g4[c];
    __syncthreads();
    stage16x128(src, row0, M, lane, alds[w]);
    for (int kk = 0; kk < 4; ++kk) {
      bf16x8 a = *(const bf16x8*)(alds[w] + swz((kk * 64 + lane) * 8));
      #pragma unroll
      for (int t = 0; t < 8; ++t) {
        bf16x8 b = *(const bf16x8*)(wlds + ((t * 4 + kk) * 64 + lane) * 8);
        acc[t] = MFMA(a, b, acc[t]);
      }
    }
  }
  float c0v[8];
  #pragma unroll
  for (int t = 0; t < 8; ++t) c0v[t] = c0n[t * 16 + m];
  float ss[8], sq[8];
  #pragma unroll
  for (int t = 0; t < 8; ++t) { ss[t] = 0.f; sq[t] = 0.f; }
  #pragma unroll
  for (int i = 0; i < 4; ++i) {
    int row = row0 + sub * 4 + i;
    if (row < M) {
      bf16x8 pk;
      #pragma unroll
      for (int t = 0; t < 8; ++t) {
        float h = acc[t][i] + c0v[t];
        pk[t] = f2bf(h); ss[t] += h; sq[t] += h * h;
      }
      *(bf16x8*)(hN + (size_t)row * 128 + m * 8) = pk;
    }
  }
  #pragma unroll
  for (int t = 0; t < 8; ++t) {
    float a = ss[t], b = sq[t];
    a += __shfl_xor(a, 16, 64); b += __shfl_xor(b, 16, 64);
    a += __shfl_xor(a, 32, 64); b += __shfl_xor(b, 32, 64);
    if (lane < 16) {
      atomicAdd(&statsLDS[t * 16 + lane], a);
      atomicAdd(&statsLDS[128 + t * 16 + lane], b);
    }
  }
  __syncthreads();
  scratchN[(size_t)blockIdx.x * 256 + tid] = statsLDS[tid];   // dense 1KB/block
}

// ---------------------------------------------------------------------------
// kD: h_e = ef@A1 + scl*(ef@A2) + edge_msg-gather(Qb bf16) + c0e ; BN stats
// R7 form (verified local optimum): 16 rows/wave, VGPR-staged L2-hot weights,
// swizzled A-frag LDS, epilogue TLP-hidden bf16 Q gather, packed 16B permuted
// hE stores, dense per-block stats, coalesced sclE read.
// ---------------------------------------------------------------------------
__global__ __launch_bounds__(256, 4) void kD(
    const float* __restrict__ ef, const short* __restrict__ WA,
    const short* __restrict__ Qb, const float* __restrict__ c0e,
    const int* __restrict__ srcI, const int* __restrict__ dstI,
    const int* __restrict__ revI, const float* __restrict__ sclE,
    short* __restrict__ hE, float* __restrict__ scratchE) {
  __shared__ __align__(16) short alds[4][2048];   // 16 rows per wave
  __shared__ __align__(16) short wbuf[8192];      // both matrices, one kk slice
  __shared__ float statsLDS[256];
  int tid = threadIdx.x, w = tid >> 6, lane = tid & 63;
  int m = lane & 15, sub = lane >> 4;
  statsLDS[tid] = 0.f;
  int row0 = blockIdx.x * 64 + w * 16;
  // prefetch per-edge index data; Q gathered in epilogue (TLP-hidden)
  float scl[4]; int qa[4], qb[4];
  #pragma unroll
  for (int i = 0; i < 4; ++i) {
    int e = row0 + sub * 4 + i;
    int s_ = srcI[e], d_ = dstI[e], r_ = revI[e];
    scl[i] = sclE[e];
    int na = r_ ? s_ : d_;
    int nb = r_ ? d_ : s_;
    qa[i] = na * 256 + m * 8;
    qb[i] = nb * 256 + 128 + m * 8;
  }
  stage16x128(ef, row0, Ee, lane, alds[w]);
  f32x4 acc1[8], acc2[8];
  #pragma unroll
  for (int t = 0; t < 8; ++t) { acc1[t] = (f32x4){0,0,0,0}; acc2[t] = (f32x4){0,0,0,0}; }
  const int4* g4 = (const int4*)WA;
  for (int kk = 0; kk < 4; ++kk) {
    __syncthreads();
    for (int c = tid; c < 1024; c += 256) {
      int mm = c >> 9, t = (c >> 6) & 7, l = c & 63;
      ((int4*)wbuf)[c] = g4[mm * 2048 + (t * 4 + kk) * 64 + l];
    }
    __syncthreads();
    bf16x8 a = *(const bf16x8*)(alds[w] + swz((kk * 64 + lane) * 8));
    #pragma unroll
    for (int t = 0; t < 8; ++t) {
      bf16x8 b1 = *(const bf16x8*)(wbuf + (t * 64 + lane) * 8);
      bf16x8 b2 = *(const bf16x8*)(wbuf + 4096 + (t * 64 + lane) * 8);
      acc1[t] = MFMA(a, b1, acc1[t]);
      acc2[t] = MFMA(a, b2, acc2[t]);
    }
  }
  float c0v[8];
  #pragma unroll
  for (int t = 0; t < 8; ++t) c0v[t] = c0e[t * 16 + m];
  float ss[8], sq[8];
  #pragma unroll
  for (int t = 0; t < 8; ++t) { ss[t] = 0.f; sq[t] = 0.f; }
  #pragma unroll
  for (int i = 0; i < 4; ++i) {
    int e = row0 + sub * 4 + i;
    u16x8 A = *(const u16x8*)(Qb + qa[i]);
    u16x8 B = *(const u16x8*)(Qb + qb[i]);
    bf16x8 pk;
    #pragma unroll
    for (int t = 0; t < 8; ++t) {
      float qv = bf2f(A[t]) - bf2f(B[t]);
      float h = acc1[t][i] + scl[i] * acc2[t][i] + qv + c0v[t];
      pk[t] = f2bf(h);
      ss[t] += h; sq[t] += h * h;
    }
    *(bf16x8*)(hE + (size_t)e * 128 + m * 8) = pk;   // permuted: [m*8+t]
  }
  #pragma unroll
  for (int t = 0; t < 8; ++t) {
    float a = ss[t], b = sq[t];
    a += __shfl_xor(a, 16, 64); b += __shfl_xor(b, 16, 64);
    a += __shfl_xor(a, 32, 64); b += __shfl_xor(b, 32, 64);
    if (lane < 16) {
      atomicAdd(&statsLDS[t * 16 + lane], a);
      atomicAdd(&statsLDS[128 + t * 16 + lane], b);
    }
  }
  __syncthreads();
  scratchE[(size_t)blockIdx.x * 256 + tid] = statsLDS[tid];   // dense 1KB/block
}

// ---------------------------------------------------------------------------
// kRed: stage-1 reduce of dense per-block stats [NB][256] -> part [64][256]
// ---------------------------------------------------------------------------
__global__ __launch_bounds__(256) void kRed(const float* __restrict__ scr, int NB,
                                            float* __restrict__ part) {
  int tid = threadIdx.x, b = blockIdx.x;
  float acc = 0.f;
  for (int r = b; r < NB; r += 64)
    acc += scr[(size_t)r * 256 + tid];
  part[b * 256 + tid] = acc;
}

// ---------------------------------------------------------------------------
// kFin: reduce part[64][256] -> s = g*rsqrt(var+eps), t = beta - mu*s
// ---------------------------------------------------------------------------
__global__ __launch_bounds__(256) void kFin(const float* __restrict__ part,
                                            float M, const float* __restrict__ g,
                                            const float* __restrict__ beta,
                                            float* __restrict__ st) {
  __shared__ float red[256];
  __shared__ float red2[256];
  int c = blockIdx.x;     // 0..127
  int tid = threadIdx.x;
  float s = 0.f, q = 0.f;
  if (tid < 64) {
    s = part[tid * 256 + c];
    q = part[tid * 256 + 128 + c];
  }
  red[tid] = s; red2[tid] = q;
  __syncthreads();
  for (int off = 32; off > 0; off >>= 1) {
    if (tid < off) { red[tid] += red[tid + off]; red2[tid] += red2[tid + off]; }
    __syncthreads();
  }
  if (tid == 0) {
    float mu  = red[0] / M;
    float var = red2[0] / M - mu * mu;
    float inv = rsqrtf(var + 1e-5f);
    float sc  = g[c] * inv;
    st[c] = sc;
    st[128 + c] = beta[c] - mu * sc;
  }
}

// ---------------------------------------------------------------------------
// kF: out = relu(h*s + t) @ w2 + b2     (h is in PERMUTED layout [m*8+t])
// w2 staged in 8KB per-kk slices -> LDS 24KB -> 6 blocks/CU.
// ---------------------------------------------------------------------------
__global__ __launch_bounds__(256, 6) void kF(const short* __restrict__ h,
                                             const float* __restrict__ st,
                                             const short* __restrict__ w2f,
                                             const float* __restrict__ b2,
                                             float* __restrict__ outp, int M) {
  __shared__ __align__(16) short alds[4][2048];
  __shared__ __align__(16) short wbuf[4096];    // one kk slice: 8 tiles
  int tid = threadIdx.x, w = tid >> 6, lane = tid & 63;
  int m2 = lane & 15;
  int row0 = blockIdx.x * 64 + w * 16;
  float sc8[8], tb8[8];
  #pragma unroll
  for (int q = 0; q < 8; ++q) {
    int col = q * 16 + m2;
    sc8[q] = st[col]; tb8[q] = st[128 + col];
  }
  #pragma unroll
  for (int it = 0; it < 4; ++it) {
    int r = it * 4 + (lane >> 4);
    int row = row0 + r;
    u16x8 hv = {0, 0, 0, 0, 0, 0, 0, 0};
    if (row < M) hv = *(const u16x8*)(h + (size_t)row * 128 + m2 * 8);
    #pragma unroll
    for (int q = 0; q < 8; ++q) {
      float f = bf2f(hv[q]);
      float v = fmaxf(f * sc8[q] + tb8[q], 0.f);
      int k = q * 16 + m2;
      int kk = k >> 5, l2 = ((k & 31) >> 3) * 16 + r, j = k & 7;
      alds[w][swz((kk * 64 + l2) * 8 + j)] = f2bf(v);
    }
  }
  f32x4 acc[8];
  #pragma unroll
  for (int t = 0; t < 8; ++t) acc[t] = (f32x4){0.f, 0.f, 0.f, 0.f};
  const int4* g4w = (const int4*)w2f;
  for (int kk = 0; kk < 4; ++kk) {
    __syncthreads();
    for (int c = tid; c < 512; c += 256) {
      int t = c >> 6, l = c & 63;
      ((int4*)wbuf)[c] = g4w[(t * 4 + kk) * 64 + l];
    }
    __syncthreads();
    bf16x8 a = *(const bf16x8*)(alds[w] + swz((kk * 64 + lane) * 8));
    #pragma unroll
    for (int t = 0; t < 8; ++t) {
      bf16x8 b = *(const bf16x8*)(wbuf + (t * 64 + lane) * 8);
      acc[t] = MFMA(a, b, acc[t]);
    }
  }
  int sub = lane >> 4;
  #pragma unroll
  for (int t = 0; t < 8; ++t) {
    int col = t * 16 + (lane & 15);
    float bb = b2[col];
    #pragma unroll
    for (int i = 0; i < 4; ++i) {
      int row = row0 + sub * 4 + i;
      if (row < M) outp[(size_t)row * 128 + col] = acc[t][i] + bb;
    }
  }
}

// ---------------------------------------------------------------------------
// kLRP: perm gather -> K=2048 GEMM over 4 of 16 a-matrices per block
// (a-split x4, grid 313*4, R5-proven form: 16KB monolithic wlds per a)
// ---------------------------------------------------------------------------
__global__ __launch_bounds__(256, 2) void kLRP(
    const float* __restrict__ nout, const float* __restrict__ eoutp,
    const int* __restrict__ n2pc, const float* __restrict__ n2pv,
    const int* __restrict__ e2pc, const float* __restrict__ e2pv,
    const int* __restrict__ poolr, const float* __restrict__ poolv,
    const short* __restrict__ WL, const float* __restrict__ lrp_bias,
    float* __restrict__ pooled) {
  __shared__ __align__(16) short alds[4][2048];
  __shared__ __align__(16) short wlds[16384];
  int tid = threadIdx.x, w = tid >> 6, lane = tid & 63;
  int blk = blockIdx.x % 313, g = blockIdx.x / 313;  // g in 0..3
  int row0 = blk * 64 + w * 16;
  int a0 = g * 4;
  f32x4 acc[8];
  #pragma unroll
  for (int t = 0; t < 8; ++t) acc[t] = (f32x4){0.f, 0.f, 0.f, 0.f};
  for (int a = a0; a < a0 + 4; ++a) {
    __syncthreads();
    const int4* g4 = (const int4*)(WL + a * 16384);
    for (int c = tid; c < 2048; c += 256) ((int4*)wlds)[c] = g4[c];
    __syncthreads();
    #pragma unroll
    for (int it = 0; it < 8; ++it) {
      int u = it * 64 + lane;
      int r = u >> 5;
      int q = u & 31;
      int d = row0 + r;
      float4 v = make_float4(0.f, 0.f, 0.f, 0.f);
      if (d < NPERMc) {
        int i = d * 16 + a;
        int nc = n2pc[i]; float nv = n2pv[i];
        int ec = e2pc[i]; float ev = e2pv[i];
        float4 nr = ((const float4*)(nout  + (size_t)nc * 128))[q];
        float4 er = ((const float4*)(eoutp + (size_t)ec * 128))[q];
        v.x = nv * nr.x + ev * er.x;
        v.y = nv * nr.y + ev * er.y;
        v.z = nv * nr.z + ev * er.z;
        v.w = nv * nr.w + ev * er.w;
      }
      int k  = q * 4;
      int kk = k >> 5;
      int l2 = ((k & 31) >> 3) * 16 + r;
      int j  = k & 7;
      s16x4 s4 = { f2bf(v.x), f2bf(v.y), f2bf(v.z), f2bf(v.w) };
      *(s16x4*)(alds[w] + swz((kk * 64 + l2) * 8 + j)) = s4;
    }
    for (int kk = 0; kk < 4; ++kk) {
      bf16x8 aa = *(const bf16x8*)(alds[w] + swz((kk * 64 + lane) * 8));
      #pragma unroll
      for (int t = 0; t < 8; ++t) {
        bf16x8 b = *(const bf16x8*)(wlds + ((t * 4 + kk) * 64 + lane) * 8);
        acc[t] = MFMA(aa, b, acc[t]);
      }
    }
  }
  int sub = lane >> 4;
  #pragma unroll
  for (int t = 0; t < 8; ++t) {
    int col = t * 16 + (lane & 15);
    float lb = (g == 0) ? lrp_bias[col] : 0.f;
    #pragma unroll
    for (int i = 0; i < 4; ++i) {
      int d = row0 + sub * 4 + i;
      if (d < NPERMc) {
        float val = acc[t][i] + lb;
        atomicAdd(&pooled[poolr[d] * 128 + col], poolv[d] * val);
      }
    }
  }
}

// ---------------------------------------------------------------------------
extern "C" void kernel_launch(void* const* d_in, const int* in_sizes, int n_in,
                              void* d_out, int out_size, void* d_ws, size_t ws_size,
                              hipStream_t stream) {
  (void)in_sizes; (void)n_in; (void)out_size; (void)ws_size;
  const float* node_feat = (const float*)d_in[0];
  const float* edge_feat = (const float*)d_in[1];
  const int*   srcI      = (const int*)d_in[2];
  const int*   dstI      = (const int*)d_in[3];
  const int*   revI      = (const int*)d_in[4];
  const int*   n2pc      = (const int*)d_in[5];
  const float* n2pv      = (const float*)d_in[6];
  const int*   e2pc      = (const int*)d_in[7];
  const float* e2pv      = (const float*)d_in[8];
  const int*   poolr     = (const int*)d_in[9];
  const float* poolv     = (const float*)d_in[10];
  const float* in_w      = (const float*)d_in[11];
  const float* out_w     = (const float*)d_in[12];
  const float* src_w     = (const float*)d_in[13];
  const float* dst_w     = (const float*)d_in[14];
  const float* nloop_w   = (const float*)d_in[15];
  const float* eloop_w   = (const float*)d_in[16];
  const float* lrp_w     = (const float*)d_in[17];
  const float* nbias     = (const float*)d_in[18];
  const float* ebias     = (const float*)d_in[19];
  const float* lrp_bias  = (const float*)d_in[20];
  const float* nmlp_w1   = (const float*)d_in[21];
  const float* nmlp_b1   = (const float*)d_in[22];
  const float* nmlp_g    = (const float*)d_in[23];
  const float* nmlp_beta = (const float*)d_in[24];
  const float* nmlp_w2   = (const float*)d_in[25];
  const float* nmlp_b2   = (const float*)d_in[26];
  const float* emlp_w1   = (const float*)d_in[27];
  const float* emlp_b1   = (const float*)d_in[28];
  const float* emlp_g    = (const float*)d_in[29];
  const float* emlp_beta = (const float*)d_in[30];
  const float* emlp_w2   = (const float*)d_in[31];
  const float* emlp_b2   = (const float*)d_in[32];

  float* pooled = (float*)d_out;             // 256*128
  float* eoutp  = (float*)d_out + 32768;     // E*128 (second output)

  char* p = (char*)d_ws;
  auto alloc = [&](size_t b) { char* r = p; p += (b + 255) & ~(size_t)255; return r; };
  short* hE   = (short*)alloc((size_t)Ee * 128 * 2);
  short* Qb   = (short*)alloc((size_t)Nn * 256 * 2);
  float* aggR = (float*)alloc((size_t)Nn * 128 * 4);
  float* aggN = (float*)alloc((size_t)Nn * 128 * 4);
  short* hN   = (short*)alloc((size_t)Nn * 128 * 2);
  float* nout = (float*)alloc((size_t)Nn * 128 * 4);
  float* deg  = (float*)alloc((size_t)Nn * 4);
  float* scrE = (float*)alloc((size_t)10000 * 256 * 4);
  float* scrN = (float*)alloc((size_t)313 * 256 * 4);
  float* partE= (float*)alloc((size_t)64 * 256 * 4);
  float* partN= (float*)alloc((size_t)64 * 256 * 4);
  float* stE  = (float*)alloc(256 * 4);
  float* stN  = (float*)alloc(256 * 4);
  short* WA   = (short*)alloc(32768 * 2);
  short* BQ   = (short*)alloc(32768 * 2);
  short* WN   = (short*)alloc(49152 * 2);
  short* W2E  = (short*)alloc(16384 * 2);
  short* W2N  = (short*)alloc(16384 * 2);
  short* WL   = (short*)alloc((size_t)16 * 16384 * 2);
  float* c0e  = (float*)alloc(128 * 4);
  float* c0n  = (float*)alloc(128 * 4);
  int*   cnt  = (int*)alloc((size_t)Nn * 4);
  int*   offA = (int*)alloc((size_t)Nn * 4);
  int*   cur  = (int*)alloc((size_t)Nn * 4);
  int*   order= (int*)alloc((size_t)Ee * 4);
  float* sclE = (float*)alloc((size_t)Ee * 4);

  hipMemsetAsync(deg,  0, (size_t)Nn * 4, stream);
  hipMemsetAsync(cnt,  0, (size_t)Nn * 4, stream);
  hipMemsetAsync(pooled, 0, (size_t)32768 * 4, stream);

  kPrep<<<1601, 256, 0, stream>>>(in_w, out_w, src_w, dst_w, nloop_w, eloop_w, lrp_w,
                                  nbias, ebias, emlp_w1, emlp_b1, nmlp_w1, nmlp_b1,
                                  emlp_w2, nmlp_w2, WA, BQ, WN, W2E, W2N, WL, c0e, c0n);
  kHist<<<Ee / 256, 256, 0, stream>>>(srcI, dstI, cnt, deg);
  kScan<<<1, 256, 0, stream>>>(cnt, offA, cur);
  kScatter<<<Ee / 256, 256, 0, stream>>>(dstI, revI, cur, order, deg, sclE);
  kAgg2<<<Nn / 4, 256, 0, stream>>>(edge_feat, offA, cnt, order, aggR, aggN);
  kQ<<<313, 256, 0, stream>>>(node_feat, BQ, Qb, Nn);
  kN1<<<313, 256, 0, stream>>>(node_feat, aggR, aggN, WN, c0n, hN, scrN, Nn);
  kD<<<10000, 256, 0, stream>>>(edge_feat, WA, Qb, c0e, srcI, dstI, revI, sclE, hE, scrE);
  kRed<<<64, 256, 0, stream>>>(scrE, 10000, partE);
  kRed<<<64, 256, 0, stream>>>(scrN, 313, partN);
  kFin<<<128, 256, 0, stream>>>(partE, (float)Ee, emlp_g, emlp_beta, stE);
  kFin<<<128, 256, 0, stream>>>(partN, (float)Nn, nmlp_g, nmlp_beta, stN);
  kF<<<10000, 256, 0, stream>>>(hE, stE, W2E, emlp_b2, eoutp, Ee);
  kF<<<313, 256, 0, stream>>>(hN, stN, W2N, nmlp_b2, nout, Nn);
  kLRP<<<1252, 256, 0, stream>>>(nout, eoutp, n2pc, n2pv, e2pc, e2pv,
                                 poolr, poolv, WL, lrp_bias, pooled);
}